// Round 2
// baseline (1832.378 us; speedup 1.0000x reference)
//
#include <hip/hip_runtime.h>
#include <hip/hip_cooperative_groups.h>

namespace cg = cooperative_groups;

#define EPSV 1e-5f
#define NBUCKET 64

typedef __attribute__((ext_vector_type(8))) short short8;
typedef __attribute__((ext_vector_type(4))) float float4v;

static inline int cdiv(int a, int b) { return (a + b - 1) / b; }
static inline int imin(int a, int b) { return a < b ? a : b; }

__device__ inline unsigned short f2bf(float x) {
  unsigned u = __float_as_uint(x);
  return (unsigned short)((u + 0x7FFFu + ((u >> 16) & 1u)) >> 16);
}
__device__ inline float bf2f(unsigned short u) {
  return __uint_as_float(((unsigned)u) << 16);
}

// 42.7 KB -> 3 blocks/CU (12 waves/CU, 3/SIMD)
struct __align__(16) SMem {
  int nbrT[64 * 27];                 // staged nbr indices for a 64-row tile
  unsigned short Bs[27 * 16 * 40];   // weight slice [27][16][CIP], CIP<=40
  float fA[64], fC[64];              // fused-BN coeffs (input channels) / tail swl+sbn
  float sA[64], sC[64];              // bn-phase coeffs
};

// ================= conv phase: MFMA gather-GEMM, grid-stride tiles =================
// Optional FUSED: input f is a RAW conv output; normalize gathered rows on the fly
// with per-channel (fA, fC) computed from fstats (bit-identical to the separate pass).
template<int CI, int CO, bool FUSED>
__device__ void conv_phase(SMem& sm,
    const unsigned short* __restrict__ f, const int* __restrict__ nbr,
    const unsigned short* __restrict__ wt, unsigned short* __restrict__ y,
    float* __restrict__ stats,
    const float* __restrict__ fstats, const float* __restrict__ fg,
    const float* __restrict__ fb, float finv_n,
    int nout, int bid, int nblocks) {
  const int tid = threadIdx.x;
  const int lane = tid & 63;
  const int wid = tid >> 6;
  const int m = lane & 15;
  const int quad = lane >> 4;
  const int ntiles = (nout + 63) >> 6;
  constexpr int ncot = (CO + 15) / 16;
  constexpr int CIP = (CI == 32) ? 40 : 24;  // LDS B stride in shorts (CI<=32)

  if constexpr (FUSED) {
    for (int o = tid; o < CI; o += 256) {
      float su = 0.f, sq = 0.f;
#pragma unroll 8
      for (int bk = 0; bk < NBUCKET; ++bk) {
        su += fstats[bk * 128 + o];
        sq += fstats[bk * 128 + 64 + o];
      }
      float mu = su * finv_n;
      float var = sq * finv_n - mu * mu;
      float a = fg[o] * rsqrtf(var + EPSV);
      sm.fA[o] = a;
      sm.fC[o] = fmaf(-mu, a, fb[o]);
    }
    // visibility covered by the __syncthreads at top of the cot loop
  }

  auto fuse8 = [&](short8 a, int cio) -> short8 {
    if constexpr (FUSED) {
#pragma unroll
      for (int q = 0; q < 8; ++q) {
        float v = bf2f((unsigned short)a[q]);
        v = fmaxf(fmaf(v, sm.fA[cio + q], sm.fC[cio + q]), 0.f);
        a[q] = (short)f2bf(v);
      }
    }
    return a;
  };

  for (int cot = 0; cot < ncot; ++cot) {
    const int cbase = cot * 16;
    const int co = cbase + m;
    const bool cok = co < CO;
    __syncthreads();
    if constexpr (CI <= 32) {
      constexpr int NC8 = CI / 8;
      for (int t = tid; t < 27 * 16 * NC8; t += 256) {
        int tap = t / (16 * NC8);
        int r = t - tap * (16 * NC8);
        int mo = r / NC8;
        int c8 = (r - mo * NC8) * 8;
        short8 v;
#pragma unroll
        for (int q = 0; q < 8; ++q) v[q] = 0;
        int c = cbase + mo;
        if (c < CO) v = *(const short8*)(wt + ((long)tap * CO + c) * CI + c8);
        *(short8*)&sm.Bs[(tap * 16 + mo) * CIP + c8] = v;
      }
    }
    __syncthreads();

    float sum = 0.f, sq = 0.f;
    for (int tile = bid; tile < ntiles; tile += nblocks) {
      const int rowb0 = tile * 64;
      {  // cooperative nbr stage: contiguous int4 loads
        const long base = (long)rowb0 * 27;
        const long lim = (long)nout * 27;
        for (int j = tid; j < 432; j += 256) {
          long g = base + j * 4;
          int4 v;
          if (g + 4 <= lim) {
            v = *(const int4*)(nbr + g);
          } else {
            v.x = (g + 0 < lim) ? nbr[g + 0] : -1;
            v.y = (g + 1 < lim) ? nbr[g + 1] : -1;
            v.z = (g + 2 < lim) ? nbr[g + 2] : -1;
            v.w = (g + 3 < lim) ? nbr[g + 3] : -1;
          }
          *(int4*)&sm.nbrT[j * 4] = v;
        }
      }
      __syncthreads();
      const int rowb = rowb0 + wid * 16;
      const int lrow = (wid * 16 + m) * 27;
      float4v acc = {0.f, 0.f, 0.f, 0.f};

      if constexpr (CI <= 16) {
        constexpr int NCHUNK = (CI == 8) ? 7 : 14;
        const int cio = (CI == 8) ? 0 : ((quad & 1) * 8);
        int idxs[NCHUNK];
#pragma unroll
        for (int c = 0; c < NCHUNK; ++c) {
          int tap = (CI == 8) ? (c * 4 + quad) : (c * 2 + (quad >> 1));
          idxs[c] = (tap < 27) ? sm.nbrT[lrow + tap] : -1;
        }
        short8 Av[NCHUNK];
#pragma unroll
        for (int c = 0; c < NCHUNK; ++c) {
          short8 a;
#pragma unroll
          for (int q = 0; q < 8; ++q) a[q] = 0;
          if (idxs[c] >= 0) a = fuse8(*(const short8*)(f + (long)idxs[c] * CI + cio), cio);
          Av[c] = a;
        }
#pragma unroll
        for (int c = 0; c < NCHUNK; ++c) {
          int tap = (CI == 8) ? (c * 4 + quad) : (c * 2 + (quad >> 1));
          int tapc = tap < 27 ? tap : 26;  // A=0 masks the clamped B
          short8 bf = *(const short8*)&sm.Bs[(tapc * 16 + m) * CIP + cio];
          acc = __builtin_amdgcn_mfma_f32_16x16x32_bf16(Av[c], bf, acc, 0, 0, 0);
        }
      } else if constexpr (CI == 32) {
        const int cio = quad * 8;
#pragma unroll
        for (int g = 0; g < 3; ++g) {
          short8 Av[9];
#pragma unroll
          for (int j = 0; j < 9; ++j) {
            int tap = g * 9 + j;
            int idx = sm.nbrT[lrow + tap];
            short8 a;
#pragma unroll
            for (int q = 0; q < 8; ++q) a[q] = 0;
            if (idx >= 0) a = fuse8(*(const short8*)(f + (long)idx * 32 + cio), cio);
            Av[j] = a;
          }
#pragma unroll
          for (int j = 0; j < 9; ++j) {
            int tap = g * 9 + j;
            short8 bf = *(const short8*)&sm.Bs[(tap * 16 + m) * CIP + cio];
            acc = __builtin_amdgcn_mfma_f32_16x16x32_bf16(Av[j], bf, acc, 0, 0, 0);
          }
        }
      } else {  // CI == 64: B from global (LDS slice would be 55 KB)
#pragma unroll
        for (int g = 0; g < 6; ++g) {
          short8 Av[9], Bv[9];
#pragma unroll
          for (int j = 0; j < 9; ++j) {
            int c = g * 9 + j;
            int tap = c >> 1;
            int cio = ((c & 1) << 5) + quad * 8;
            int idx = sm.nbrT[lrow + tap];
            short8 a, bq;
#pragma unroll
            for (int q = 0; q < 8; ++q) { a[q] = 0; bq[q] = 0; }
            if (idx >= 0) a = fuse8(*(const short8*)(f + (long)idx * 64 + cio), cio);
            if (cok) bq = *(const short8*)(wt + ((long)tap * CO + co) * 64 + cio);
            Av[j] = a; Bv[j] = bq;
          }
#pragma unroll
          for (int j = 0; j < 9; ++j)
            acc = __builtin_amdgcn_mfma_f32_16x16x32_bf16(Av[j], Bv[j], acc, 0, 0, 0);
        }
      }

#pragma unroll
      for (int r = 0; r < 4; ++r) {
        float v = acc[r];
        int orow = rowb + quad * 4 + r;
        if (cok && orow < nout) y[(long)orow * CO + co] = f2bf(v);
        sum += v;
        sq = fmaf(v, v, sq);
      }
      __syncthreads();
    }
    sum += __shfl_xor(sum, 16); sq += __shfl_xor(sq, 16);
    sum += __shfl_xor(sum, 32); sq += __shfl_xor(sq, 32);
    if (quad == 0 && cok) {
      float* st = stats + ((((unsigned)bid * 4 + wid) & (NBUCKET - 1)) << 7);
      atomicAdd(st + co, sum);
      atomicAdd(st + 64 + co, sq);
    }
  }
}

// ---- BN+ReLU (+bf16 skip) materialization, grid-stride ----
template<int CO>
__device__ void bn_phase(float* sA, float* sC,
    const unsigned short* __restrict__ y, const float* __restrict__ stats,
    const float* __restrict__ g, const float* __restrict__ b,
    const unsigned short* __restrict__ skip, unsigned short* __restrict__ out,
    int nout, float inv_n, int bid, int nblocks) {
  for (int o = threadIdx.x; o < CO; o += 256) {
    float su = 0.f, sq = 0.f;
#pragma unroll 8
    for (int bk = 0; bk < NBUCKET; ++bk) {
      su += stats[bk * 128 + o];
      sq += stats[bk * 128 + 64 + o];
    }
    float mu = su * inv_n;
    float var = sq * inv_n - mu * mu;
    float a = g[o] * rsqrtf(var + EPSV);
    sA[o] = a;
    sC[o] = fmaf(-mu, a, b[o]);
  }
  __syncthreads();
  long total4 = (long)nout * CO / 4;
  for (long i4 = (long)bid * 256 + threadIdx.x; i4 < total4;
       i4 += (long)nblocks * 256) {
    int o = (int)((i4 * 4) % CO);
    ushort4 v = ((const ushort4*)y)[i4];
    float vv[4] = {bf2f(v.x), bf2f(v.y), bf2f(v.z), bf2f(v.w)};
    unsigned short rr[4];
#pragma unroll
    for (int j = 0; j < 4; ++j) {
      float x = fmaxf(fmaf(vv[j], sA[o + j], sC[o + j]), 0.f);
      if (skip) x += bf2f(skip[i4 * 4 + j]);
      rr[j] = f2bf(x);
    }
    ushort4 r;
    r.x = rr[0]; r.y = rr[1]; r.z = rr[2]; r.w = rr[3];
    ((ushort4*)out)[i4] = r;
  }
}

// ---- fused tail: x0 = c0f + relu(bn(y9)); out0 = x0 @ lin_w.T ----
__device__ void tail_phase(float* swl, float* sbn,
    const unsigned short* __restrict__ c0f, const float* __restrict__ st9,
    const float* __restrict__ g9, const float* __restrict__ b9, float inv_n,
    const float* __restrict__ lin_w, const unsigned short* __restrict__ y9,
    float* __restrict__ out0, float* __restrict__ x0, int n0,
    int bid, int nblocks) {
  if (threadIdx.x < 64) swl[threadIdx.x] = lin_w[threadIdx.x];
  if (threadIdx.x < 8) {
    int o = threadIdx.x;
    float su = 0.f, sq = 0.f;
#pragma unroll 8
    for (int bk = 0; bk < NBUCKET; ++bk) {
      su += st9[bk * 128 + o];
      sq += st9[bk * 128 + 64 + o];
    }
    float mu = su * inv_n;
    float var = sq * inv_n - mu * mu;
    float a = g9[o] * rsqrtf(var + EPSV);
    sbn[o] = a;
    sbn[8 + o] = fmaf(-mu, a, b9[o]);
  }
  __syncthreads();
  for (int n = bid * 256 + (int)threadIdx.x; n < n0; n += nblocks * 256) {
    const ushort4* pr = (const ushort4*)(y9 + (long)n * 8);
    ushort4 r0 = pr[0], r1 = pr[1];
    unsigned short rw[8] = {r0.x, r0.y, r0.z, r0.w, r1.x, r1.y, r1.z, r1.w};
    const ushort4* pc = (const ushort4*)(c0f + (long)n * 8);
    ushort4 c0 = pc[0], c1 = pc[1];
    unsigned short cs[8] = {c0.x, c0.y, c0.z, c0.w, c1.x, c1.y, c1.z, c1.w};
    float xv[8];
#pragma unroll
    for (int c = 0; c < 8; ++c)
      xv[c] = bf2f(cs[c]) + fmaxf(fmaf(bf2f(rw[c]), sbn[c], sbn[8 + c]), 0.f);
    *(float4*)(x0 + (long)n * 8) = make_float4(xv[0], xv[1], xv[2], xv[3]);
    *(float4*)(x0 + (long)n * 8 + 4) = make_float4(xv[4], xv[5], xv[6], xv[7]);
    float ov[8];
#pragma unroll
    for (int j = 0; j < 8; ++j) {
      float s = 0.f;
#pragma unroll
      for (int c = 0; c < 8; ++c) s = fmaf(xv[c], swl[j * 8 + c], s);
      ov[j] = s;
    }
    *(float4*)(out0 + (long)n * 8) = make_float4(ov[0], ov[1], ov[2], ov[3]);
    *(float4*)(out0 + (long)n * 8 + 4) = make_float4(ov[4], ov[5], ov[6], ov[7]);
  }
}

// ================= persistent cooperative mono-kernel =================
struct MonoArgs {
  const float* feats;
  const int* nbr[10];
  const float* w[10];
  const float* g[10];
  const float* b[10];
  const float* lin_w;
  float* stats;
  unsigned short* wt[10];
  unsigned short* featsb;
  unsigned short* yA;
  unsigned short* yB;
  unsigned short* c0f;
  unsigned short* c2f;
  unsigned short* c4f;
  unsigned short* t5;
  unsigned short* t6;
  float* out0;
  float* x0;
  int wcum[11];
  int ciArr[10];
  int coArr[10];
  int N0, N1, N2, N3, nfeat4;
  float i0, i1, i2, i3;
};

__device__ void prep_phase(const MonoArgs& A, int bid, int nblocks) {
  const int nstat4 = 10 * NBUCKET * 128 / 4;
  const long total = (long)nstat4 + A.nfeat4 + A.wcum[10];
  for (long t0 = (long)bid * 256 + threadIdx.x; t0 < total;
       t0 += (long)nblocks * 256) {
    long t = t0;
    if (t < nstat4) {
      ((float4*)A.stats)[t] = make_float4(0.f, 0.f, 0.f, 0.f);
      continue;
    }
    t -= nstat4;
    if (t < A.nfeat4) {
      float4 v = ((const float4*)A.feats)[t];
      ushort4 r;
      r.x = f2bf(v.x); r.y = f2bf(v.y); r.z = f2bf(v.z); r.w = f2bf(v.w);
      ((ushort4*)A.featsb)[t] = r;
      continue;
    }
    t -= A.nfeat4;
    int i = 0;
    while (t >= A.wcum[i + 1]) ++i;
    int e = (int)(t - A.wcum[i]);
    int ci = A.ciArr[i], co = A.coArr[i];
    int k = e / (ci * co);
    int r = e - k * (ci * co);
    int o = r / ci;
    int c = r - o * ci;
    A.wt[i][((long)k * co + o) * ci + c] = f2bf(A.w[i][((long)k * ci + c) * co + o]);
  }
}

__global__ __launch_bounds__(256, 3) void mono_kernel(MonoArgs A) {
  cg::grid_group grid = cg::this_grid();
  __shared__ SMem sm;
  const int bid = (int)blockIdx.x;
  const int nb = (int)gridDim.x;
#define GSYNC() do { __threadfence(); grid.sync(); __threadfence(); } while (0)
  float* S[10];
#pragma unroll
  for (int i = 0; i < 10; ++i) S[i] = A.stats + i * NBUCKET * 128;

  prep_phase(A, bid, nb);
  GSYNC();
  conv_phase<16, 8, false>(sm, A.featsb, A.nbr[0], A.wt[0], A.yA, S[0], nullptr, nullptr, nullptr, 0.f, A.N0, bid, nb);
  GSYNC();
  bn_phase<8>(sm.sA, sm.sC, A.yA, S[0], A.g[0], A.b[0], nullptr, A.c0f, A.N0, A.i0, bid, nb);
  GSYNC();
  conv_phase<8, 16, false>(sm, A.c0f, A.nbr[1], A.wt[1], A.yA, S[1], nullptr, nullptr, nullptr, 0.f, A.N1, bid, nb);
  GSYNC();
  conv_phase<16, 16, true>(sm, A.yA, A.nbr[2], A.wt[2], A.yB, S[2], S[1], A.g[1], A.b[1], A.i1, A.N1, bid, nb);
  GSYNC();
  bn_phase<16>(sm.sA, sm.sC, A.yB, S[2], A.g[2], A.b[2], nullptr, A.c2f, A.N1, A.i1, bid, nb);
  GSYNC();
  conv_phase<16, 32, false>(sm, A.c2f, A.nbr[3], A.wt[3], A.yA, S[3], nullptr, nullptr, nullptr, 0.f, A.N2, bid, nb);
  GSYNC();
  conv_phase<32, 32, true>(sm, A.yA, A.nbr[4], A.wt[4], A.yB, S[4], S[3], A.g[3], A.b[3], A.i2, A.N2, bid, nb);
  GSYNC();
  bn_phase<32>(sm.sA, sm.sC, A.yB, S[4], A.g[4], A.b[4], nullptr, A.c4f, A.N2, A.i2, bid, nb);
  GSYNC();
  conv_phase<32, 64, false>(sm, A.c4f, A.nbr[5], A.wt[5], A.yA, S[5], nullptr, nullptr, nullptr, 0.f, A.N3, bid, nb);
  GSYNC();
  conv_phase<64, 64, true>(sm, A.yA, A.nbr[6], A.wt[6], A.yB, S[6], S[5], A.g[5], A.b[5], A.i3, A.N3, bid, nb);
  GSYNC();
  conv_phase<64, 32, true>(sm, A.yB, A.nbr[7], A.wt[7], A.yA, S[7], S[6], A.g[6], A.b[6], A.i3, A.N2, bid, nb);
  GSYNC();
  bn_phase<32>(sm.sA, sm.sC, A.yA, S[7], A.g[7], A.b[7], A.c4f, A.t5, A.N2, A.i2, bid, nb);
  GSYNC();
  conv_phase<32, 16, false>(sm, A.t5, A.nbr[8], A.wt[8], A.yB, S[8], nullptr, nullptr, nullptr, 0.f, A.N1, bid, nb);
  GSYNC();
  bn_phase<16>(sm.sA, sm.sC, A.yB, S[8], A.g[8], A.b[8], A.c2f, A.t6, A.N1, A.i1, bid, nb);
  GSYNC();
  conv_phase<16, 8, false>(sm, A.t6, A.nbr[9], A.wt[9], A.yA, S[9], nullptr, nullptr, nullptr, 0.f, A.N0, bid, nb);
  GSYNC();
  tail_phase(sm.fA, sm.fC, A.c0f, S[9], A.g[9], A.b[9], A.i0, A.lin_w, A.yA, A.out0, A.x0, A.N0, bid, nb);
#undef GSYNC
}

// ================= fallback multi-kernel path (round-1 behavior) =================
struct PrepArgs {
  const float* w[10];
  unsigned short* wt[10];
  int ci[10];
  int co[10];
  int wcum[11];
  const float* feats;
  unsigned short* featsb;
  int nfeat4;
  float* stats;
};

__global__ __launch_bounds__(256) void prep_kernel(PrepArgs p, long total) {
  const int nstat4 = 10 * NBUCKET * 128 / 4;
  for (long tid0 = (long)blockIdx.x * 256 + threadIdx.x; tid0 < total;
       tid0 += (long)gridDim.x * 256) {
    long tid = tid0;
    if (tid < nstat4) {
      ((float4*)p.stats)[tid] = make_float4(0.f, 0.f, 0.f, 0.f);
      continue;
    }
    tid -= nstat4;
    if (tid < p.nfeat4) {
      float4 v = ((const float4*)p.feats)[tid];
      ushort4 r;
      r.x = f2bf(v.x); r.y = f2bf(v.y); r.z = f2bf(v.z); r.w = f2bf(v.w);
      ((ushort4*)p.featsb)[tid] = r;
      continue;
    }
    tid -= p.nfeat4;
    if (tid >= p.wcum[10]) continue;
    int i = 0;
    while (tid >= p.wcum[i + 1]) ++i;
    int e = (int)(tid - p.wcum[i]);
    int ci = p.ci[i], co = p.co[i];
    int k = e / (ci * co);
    int r = e - k * (ci * co);
    int o = r / ci;
    int c = r - o * ci;
    p.wt[i][((long)k * co + o) * ci + c] = f2bf(p.w[i][((long)k * ci + c) * co + o]);
  }
}

template<int CI, int CO>
__global__ __launch_bounds__(256, 3) void conv_kernel(
    const unsigned short* __restrict__ f, const int* __restrict__ nbr,
    const unsigned short* __restrict__ wt, unsigned short* __restrict__ y,
    float* __restrict__ stats, int nout) {
  __shared__ SMem sm;
  conv_phase<CI, CO, false>(sm, f, nbr, wt, y, stats, nullptr, nullptr, nullptr,
                            0.f, nout, (int)blockIdx.x, (int)gridDim.x);
}

template<int CO>
__global__ __launch_bounds__(256) void bn_kernel(
    const unsigned short* __restrict__ y, const float* __restrict__ stats,
    const float* __restrict__ g, const float* __restrict__ b,
    const unsigned short* __restrict__ skip, unsigned short* __restrict__ out,
    int nout, float inv_n) {
  __shared__ float sA[CO], sC[CO];
  bn_phase<CO>(sA, sC, y, stats, g, b, skip, out, nout, inv_n,
               (int)blockIdx.x, (int)gridDim.x);
}

__global__ __launch_bounds__(256) void tail_kernel(
    const unsigned short* __restrict__ c0f, const float* __restrict__ st9,
    const float* __restrict__ g9, const float* __restrict__ b9, float inv_n,
    const float* __restrict__ lin_w, const unsigned short* __restrict__ y9,
    float* __restrict__ out0, float* __restrict__ x0, int n0) {
  __shared__ float swl[64];
  __shared__ float sbn[16];
  tail_phase(swl, sbn, c0f, st9, g9, b9, inv_n, lin_w, y9, out0, x0, n0,
             (int)blockIdx.x, (int)gridDim.x);
}

extern "C" void kernel_launch(void* const* d_in, const int* in_sizes, int n_in,
                              void* d_out, int out_size, void* d_ws, size_t ws_size,
                              hipStream_t stream) {
  const float* feats = (const float*)d_in[0];
  const int* nbrs[10];
  for (int i = 0; i < 10; ++i) nbrs[i] = (const int*)d_in[1 + i];
  const float* w[10];
  const float* g[10];
  const float* b[10];
  for (int i = 0; i < 10; ++i) {
    w[i] = (const float*)d_in[11 + 3 * i];
    g[i] = (const float*)d_in[12 + 3 * i];
    b[i] = (const float*)d_in[13 + 3 * i];
  }
  const float* lin_w = (const float*)d_in[41];

  const int N0 = in_sizes[0] / 16;
  const int N1 = in_sizes[2] / 27;
  const int N2 = in_sizes[4] / 27;
  const int N3 = in_sizes[6] / 27;
  const float i0 = 1.f / N0, i1 = 1.f / N1, i2 = 1.f / N2, i3 = 1.f / N3;

  static const int CIv[10] = {16, 8, 16, 16, 32, 32, 64, 64, 32, 16};
  static const int COv[10] = {8, 16, 16, 32, 32, 64, 64, 32, 16, 8};

  // ---- workspace layout ----
  float* stats = (float*)d_ws;  // 10 x NBUCKET x 128 floats
  unsigned short* u = (unsigned short*)(stats + 10 * NBUCKET * 128);

  unsigned short* wt[10];
  int wcum[11];
  wcum[0] = 0;
  for (int i = 0; i < 10; ++i) {
    wt[i] = u;
    int sz = 27 * CIv[i] * COv[i];
    u += sz;
    wcum[i + 1] = wcum[i] + sz;
  }
  size_t ymax = (size_t)N0 * 8;
  if ((size_t)N1 * 16 > ymax) ymax = (size_t)N1 * 16;
  if ((size_t)N2 * 32 > ymax) ymax = (size_t)N2 * 32;
  if ((size_t)N3 * 64 > ymax) ymax = (size_t)N3 * 64;

  unsigned short* featsb = u; u += (size_t)N0 * 16;
  unsigned short* yA = u;     u += ymax;
  unsigned short* yB = u;     u += ymax;
  unsigned short* c0f = u;    u += (size_t)N0 * 8;
  unsigned short* c2f = u;    u += (size_t)N1 * 16;
  unsigned short* c4f = u;    u += (size_t)N2 * 32;
  unsigned short* t1 = u;     u += (size_t)N1 * 16;
  unsigned short* t2 = u;     u += (size_t)N2 * 32;
  unsigned short* t3 = u;     u += (size_t)N3 * 64;
  unsigned short* t4 = u;     u += (size_t)N3 * 64;
  unsigned short* t5 = u;     u += (size_t)N2 * 32;
  unsigned short* t6 = u;     u += (size_t)N1 * 16;
  float* out0 = (float*)d_out;
  float* x0 = (float*)d_out + (size_t)N0 * 8;

  float* s[10];
  for (int i = 0; i < 10; ++i) s[i] = stats + i * NBUCKET * 128;

  // ---- persistent cooperative mono-kernel ----
  static int s_nblk = 0;
  if (s_nblk == 0) {
    int dev = 0;
    hipGetDevice(&dev);
    hipDeviceProp_t prop{};
    hipGetDeviceProperties(&prop, dev);
    int ncu = prop.multiProcessorCount > 0 ? prop.multiProcessorCount : 256;
    int per = 0;
    hipError_t oe = hipOccupancyMaxActiveBlocksPerMultiprocessor(&per, mono_kernel, 256, 0);
    if (oe != hipSuccess || per < 1) per = 1;
    s_nblk = imin(per, 4) * ncu;
  }

  MonoArgs MA;
  MA.feats = feats;
  for (int i = 0; i < 10; ++i) {
    MA.nbr[i] = nbrs[i];
    MA.w[i] = w[i]; MA.g[i] = g[i]; MA.b[i] = b[i];
    MA.wt[i] = wt[i];
    MA.wcum[i] = wcum[i];
    MA.ciArr[i] = CIv[i]; MA.coArr[i] = COv[i];
  }
  MA.wcum[10] = wcum[10];
  MA.lin_w = lin_w;
  MA.stats = stats;
  MA.featsb = featsb;
  MA.yA = yA; MA.yB = yB;
  MA.c0f = c0f; MA.c2f = c2f; MA.c4f = c4f;
  MA.t5 = t5; MA.t6 = t6;
  MA.out0 = out0; MA.x0 = x0;
  MA.N0 = N0; MA.N1 = N1; MA.N2 = N2; MA.N3 = N3;
  MA.nfeat4 = N0 * 16 / 4;
  MA.i0 = i0; MA.i1 = i1; MA.i2 = i2; MA.i3 = i3;

  void* kargs[] = {(void*)&MA};
  hipError_t e = hipLaunchCooperativeKernel(mono_kernel, dim3(s_nblk), dim3(256),
                                            kargs, 0, stream);
  if (e == hipSuccess) return;
  (void)hipGetLastError();

  // ---- fallback: multi-kernel path ----
  PrepArgs pa;
  for (int i = 0; i < 10; ++i) {
    pa.w[i] = w[i]; pa.wt[i] = wt[i];
    pa.ci[i] = CIv[i]; pa.co[i] = COv[i];
    pa.wcum[i] = wcum[i];
  }
  pa.wcum[10] = wcum[10];
  pa.feats = feats; pa.featsb = featsb;
  pa.nfeat4 = N0 * 16 / 4;
  pa.stats = stats;
  long prep_total = (10 * NBUCKET * 128 / 4) + pa.nfeat4 + wcum[10];
  prep_kernel<<<imin((int)((prep_total + 255) / 256), 2048), 256, 0, stream>>>(pa, prep_total);

  auto bgrid = [](long nout, int co) {
    return imin((int)((nout * co / 4 + 255) / 256), 1024);
  };
  auto cgrid = [](int ntiles) { return imin(ntiles, 2048); };
  int tb0 = cdiv(N0, 64), tb1 = cdiv(N1, 64), tb2 = cdiv(N2, 64), tb3 = cdiv(N3, 64);

  conv_kernel<16, 8><<<cgrid(tb0), 256, 0, stream>>>(featsb, nbrs[0], wt[0], yA, s[0], N0);
  bn_kernel<8><<<bgrid(N0, 8), 256, 0, stream>>>(yA, s[0], g[0], b[0], nullptr, c0f, N0, i0);
  conv_kernel<8, 16><<<cgrid(tb1), 256, 0, stream>>>(c0f, nbrs[1], wt[1], yA, s[1], N1);
  bn_kernel<16><<<bgrid(N1, 16), 256, 0, stream>>>(yA, s[1], g[1], b[1], nullptr, t1, N1, i1);
  conv_kernel<16, 16><<<cgrid(tb1), 256, 0, stream>>>(t1, nbrs[2], wt[2], yA, s[2], N1);
  bn_kernel<16><<<bgrid(N1, 16), 256, 0, stream>>>(yA, s[2], g[2], b[2], nullptr, c2f, N1, i1);
  conv_kernel<16, 32><<<cgrid(tb2), 256, 0, stream>>>(c2f, nbrs[3], wt[3], yA, s[3], N2);
  bn_kernel<32><<<bgrid(N2, 32), 256, 0, stream>>>(yA, s[3], g[3], b[3], nullptr, t2, N2, i2);
  conv_kernel<32, 32><<<cgrid(tb2), 256, 0, stream>>>(t2, nbrs[4], wt[4], yA, s[4], N2);
  bn_kernel<32><<<bgrid(N2, 32), 256, 0, stream>>>(yA, s[4], g[4], b[4], nullptr, c4f, N2, i2);
  conv_kernel<32, 64><<<cgrid(tb3), 256, 0, stream>>>(c4f, nbrs[5], wt[5], yA, s[5], N3);
  bn_kernel<64><<<bgrid(N3, 64), 256, 0, stream>>>(yA, s[5], g[5], b[5], nullptr, t3, N3, i3);
  conv_kernel<64, 64><<<cgrid(tb3), 256, 0, stream>>>(t3, nbrs[6], wt[6], yA, s[6], N3);
  bn_kernel<64><<<bgrid(N3, 64), 256, 0, stream>>>(yA, s[6], g[6], b[6], nullptr, t4, N3, i3);
  conv_kernel<64, 32><<<cgrid(tb2), 256, 0, stream>>>(t4, nbrs[7], wt[7], yA, s[7], N2);
  bn_kernel<32><<<bgrid(N2, 32), 256, 0, stream>>>(yA, s[7], g[7], b[7], c4f, t5, N2, i2);
  conv_kernel<32, 16><<<cgrid(tb1), 256, 0, stream>>>(t5, nbrs[8], wt[8], yA, s[8], N1);
  bn_kernel<16><<<bgrid(N1, 16), 256, 0, stream>>>(yA, s[8], g[8], b[8], c2f, t6, N1, i1);
  conv_kernel<16, 8><<<cgrid(tb0), 256, 0, stream>>>(t6, nbrs[9], wt[9], yA, s[9], N0);
  tail_kernel<<<imin(cdiv(N0, 256), 1024), 256, 0, stream>>>(
      c0f, s[9], g[9], b[9], i0, lin_w, yA, out0, x0, N0);
}

// Round 3
// 474.847 us; speedup vs baseline: 3.8589x; 3.8589x over previous
//
#include <hip/hip_runtime.h>

#define EPSV 1e-5f
#define NBUCKET 64

typedef __attribute__((ext_vector_type(8))) short short8;
typedef __attribute__((ext_vector_type(4))) float float4v;

static inline int cdiv(int a, int b) { return (a + b - 1) / b; }
static inline int imin(int a, int b) { return a < b ? a : b; }

__device__ inline unsigned short f2bf(float x) {
  unsigned u = __float_as_uint(x);
  return (unsigned short)((u + 0x7FFFu + ((u >> 16) & 1u)) >> 16);
}
__device__ inline float bf2f(unsigned short u) {
  return __uint_as_float(((unsigned)u) << 16);
}

struct PrepArgs {
  const float* w[10];
  unsigned short* wt[10];
  int ci[10];
  int co[10];
  int wcum[11];
  const float* feats;
  unsigned short* featsb;
  int nfeat4;
  float* stats;
};

// grid-stride: zero stats + feats fp32->bf16 + weights fp32->bf16 transposed [27][CO][CI]
__global__ __launch_bounds__(256) void prep_kernel(PrepArgs p, long total) {
  const int nstat4 = 10 * NBUCKET * 128 / 4;
  for (long tid0 = (long)blockIdx.x * 256 + threadIdx.x; tid0 < total;
       tid0 += (long)gridDim.x * 256) {
    long tid = tid0;
    if (tid < nstat4) {
      ((float4*)p.stats)[tid] = make_float4(0.f, 0.f, 0.f, 0.f);
      continue;
    }
    tid -= nstat4;
    if (tid < p.nfeat4) {
      float4 v = ((const float4*)p.feats)[tid];
      ushort4 r;
      r.x = f2bf(v.x); r.y = f2bf(v.y); r.z = f2bf(v.z); r.w = f2bf(v.w);
      ((ushort4*)p.featsb)[tid] = r;
      continue;
    }
    tid -= p.nfeat4;
    if (tid >= p.wcum[10]) continue;
    int i = 0;
    while (tid >= p.wcum[i + 1]) ++i;
    int e = (int)(tid - p.wcum[i]);
    int ci = p.ci[i], co = p.co[i];
    int k = e / (ci * co);
    int r = e - k * (ci * co);
    int o = r / ci;
    int c = r - o * ci;
    p.wt[i][((long)k * co + o) * ci + c] = f2bf(p.w[i][((long)k * ci + c) * co + o]);
  }
}

// ================= MFMA gather-GEMM conv (round-1 proven structure) =================
// Block = 4 waves; wave handles one 16-row MFMA tile per 64-row block-tile, looping
// tiles with stride gridDim.x; gridDim.y tiles CO in 16-wide slices.
// nbr indices staged cooperatively through LDS (coalesced int4 -> ds_read).
// Weight slice [27][16][CI] staged in LDS once per block.
// FUSED: input f is a RAW conv output; per-channel BN+ReLU coeffs (from fstats)
// are applied to gathered rows in registers -- bit-identical to a separate BN pass.
template<int CI, int CO, bool FUSED, int MINW>
__global__ __launch_bounds__(256, MINW) void conv_mfma(
    const unsigned short* __restrict__ f, const int* __restrict__ nbr,
    const unsigned short* __restrict__ wt, unsigned short* __restrict__ y,
    float* __restrict__ stats,
    const float* __restrict__ fstats, const float* __restrict__ fg,
    const float* __restrict__ fb, float finv_n,
    int nout, int ntiles) {
  constexpr int NCHUNK = (CI == 8) ? 7 : (CI == 16) ? 14 : (CI == 32) ? 27 : 54;
  constexpr int CIP = (CI == 64) ? 64 : (CI == 32) ? 40 : 24;
  constexpr int NFR = (CI == 64) ? 16 : 8;  // per-lane fused-BN channels

  __shared__ int nbrT[64 * 27];
  __shared__ unsigned short Bs[27 * 16 * CIP];
  __shared__ float fsh[FUSED ? 2 * CI : 4];

  const int tid = threadIdx.x;
  const int lane = tid & 63;
  const int wid = tid >> 6;
  const int m = lane & 15;
  const int quad = lane >> 4;
  const int cbase = blockIdx.y * 16;
  const int co = cbase + m;
  const bool cok = co < CO;

  auto tapof = [&](int c) -> int {
    if constexpr (CI == 8) return c * 4 + quad;
    else if constexpr (CI == 16) return c * 2 + (quad >> 1);
    else if constexpr (CI == 32) return c;
    else return c >> 1;
  };
  auto cioof = [&](int c) -> int {
    if constexpr (CI == 8) return 0;
    else if constexpr (CI == 16) return (quad & 1) * 8;
    else if constexpr (CI == 32) return quad * 8;
    else return ((c & 1) << 5) + quad * 8;
  };
  // LDS B address (short index) for [tap][mm][cio]
  auto baddr = [&](int tap, int mm, int cio) -> int {
    if constexpr (CI == 64) {
      int byt = (tap * 16 + mm) * 128 + cio * 2;
      byt ^= (mm & 7) << 4;  // XOR-swizzle 16B slot within the 128B row
      return byt >> 1;
    } else {
      return (tap * 16 + mm) * CIP + cio;
    }
  };

  // ---- fused-BN coefficient reduction (once per block) ----
  if constexpr (FUSED) {
    for (int o = tid; o < CI; o += 256) {
      float su = 0.f, sq = 0.f;
#pragma unroll 8
      for (int bk = 0; bk < NBUCKET; ++bk) {
        su += fstats[bk * 128 + o];
        sq += fstats[bk * 128 + 64 + o];
      }
      float mu = su * finv_n;
      float var = sq * finv_n - mu * mu;
      float a = fg[o] * rsqrtf(var + EPSV);
      fsh[o] = a;
      fsh[CI + o] = fmaf(-mu, a, fb[o]);
    }
  }

  // ---- cooperative weight-slice load into LDS (once per block) ----
  {
    constexpr int NC8 = CI / 8;
    for (int t = tid; t < 27 * 16 * NC8; t += 256) {
      int tap = t / (16 * NC8);
      int r = t - tap * (16 * NC8);
      int mo = r / NC8;
      int c8 = (r - mo * NC8) * 8;
      short8 v;
#pragma unroll
      for (int q = 0; q < 8; ++q) v[q] = 0;
      int c = cbase + mo;
      if (c < CO) v = *(const short8*)(wt + ((long)tap * CO + c) * CI + c8);
      *(short8*)&Bs[baddr(tap, mo, c8)] = v;
    }
  }
  __syncthreads();  // order fsh + Bs fill before register loads / first tile

  // ---- per-lane fused-BN coeffs into registers ----
  float fAr[NFR], fCr[NFR];
  if constexpr (FUSED) {
    if constexpr (CI == 64) {
#pragma unroll
      for (int h = 0; h < 2; ++h)
#pragma unroll
        for (int q = 0; q < 8; ++q) {
          fAr[h * 8 + q] = fsh[h * 32 + quad * 8 + q];
          fCr[h * 8 + q] = fsh[CI + h * 32 + quad * 8 + q];
        }
    } else {
      const int cio0 = (CI == 8) ? 0 : (CI == 16) ? (quad & 1) * 8 : quad * 8;
#pragma unroll
      for (int q = 0; q < 8; ++q) {
        fAr[q] = fsh[cio0 + q];
        fCr[q] = fsh[CI + cio0 + q];
      }
    }
  } else {
    (void)fAr; (void)fCr;
  }

  auto fuse8 = [&](short8 a, int fb8) -> short8 {
    if constexpr (FUSED) {
#pragma unroll
      for (int q = 0; q < 8; ++q) {
        float v = bf2f((unsigned short)a[q]);
        v = fmaxf(fmaf(v, fAr[fb8 + q], fCr[fb8 + q]), 0.f);
        a[q] = (short)f2bf(v);
      }
    }
    return a;
  };

  float sum = 0.f, sq = 0.f;

  for (int tile = blockIdx.x; tile < ntiles; tile += gridDim.x) {
    const int rowb0 = tile * 64;
    // ---- cooperative nbr stage: contiguous int4 loads ----
    {
      const long base = (long)rowb0 * 27;
      const long lim = (long)nout * 27;
      for (int j = tid; j < 432; j += 256) {  // 432 int4 = 1728 ints
        long g = base + j * 4;
        int4 v;
        if (g + 4 <= lim) {
          v = *(const int4*)(nbr + g);
        } else {
          v.x = (g + 0 < lim) ? nbr[g + 0] : -1;
          v.y = (g + 1 < lim) ? nbr[g + 1] : -1;
          v.z = (g + 2 < lim) ? nbr[g + 2] : -1;
          v.w = (g + 3 < lim) ? nbr[g + 3] : -1;
        }
        *(int4*)&nbrT[j * 4] = v;
      }
    }
    __syncthreads();

    const int rowb = rowb0 + wid * 16;
    const int lrow = (wid * 16 + m) * 27;
    float4v acc = {0.f, 0.f, 0.f, 0.f};

    if constexpr (CI <= 16) {
      int idxs[NCHUNK];
#pragma unroll
      for (int c = 0; c < NCHUNK; ++c) {
        int tap = tapof(c);
        idxs[c] = (tap < 27) ? nbrT[lrow + tap] : -1;
      }
      short8 A[NCHUNK];
#pragma unroll
      for (int c = 0; c < NCHUNK; ++c) {
        short8 a;
#pragma unroll
        for (int q = 0; q < 8; ++q) a[q] = 0;
        if (idxs[c] >= 0) a = fuse8(*(const short8*)(f + (long)idxs[c] * CI + cioof(c)), 0);
        A[c] = a;
      }
#pragma unroll
      for (int c = 0; c < NCHUNK; ++c) {
        int tap = tapof(c);
        int tapc = tap < 27 ? tap : 26;  // A=0 masks the clamped B
        short8 bf = *(const short8*)&Bs[baddr(tapc, m, cioof(c))];
        acc = __builtin_amdgcn_mfma_f32_16x16x32_bf16(A[c], bf, acc, 0, 0, 0);
      }
    } else {
      constexpr int G = 9;
      constexpr int NG = NCHUNK / G;
      short8 A[2][G];
      auto load_group = [&](int g, int bi) {
#pragma unroll
        for (int j = 0; j < G; ++j) {
          const int c = g * G + j;
          const int tap = tapof(c);
          int idx = nbrT[lrow + tap];
          short8 a;
#pragma unroll
          for (int q = 0; q < 8; ++q) a[q] = 0;
          if (idx >= 0)
            a = fuse8(*(const short8*)(f + (long)idx * CI + cioof(c)),
                      (CI == 64) ? ((c & 1) * 8) : 0);
          A[bi][j] = a;
        }
      };
      load_group(0, 0);
#pragma unroll
      for (int g = 0; g < NG; ++g) {
        const int cur = g & 1;
        if (g + 1 < NG) load_group(g + 1, cur ^ 1);
#pragma unroll
        for (int j = 0; j < G; ++j) {
          const int c = g * G + j;
          short8 bf = *(const short8*)&Bs[baddr(tapof(c), m, cioof(c))];
          acc = __builtin_amdgcn_mfma_f32_16x16x32_bf16(A[cur][j], bf, acc, 0, 0, 0);
        }
      }
    }

#pragma unroll
    for (int r = 0; r < 4; ++r) {
      float v = acc[r];
      int orow = rowb + quad * 4 + r;
      if (cok && orow < nout) y[(long)orow * CO + co] = f2bf(v);
      sum += v;
      sq = fmaf(v, v, sq);
    }
    __syncthreads();  // nbrT reused next iteration
  }

  // one atomic pair per wave
  sum += __shfl_xor(sum, 16); sq += __shfl_xor(sq, 16);
  sum += __shfl_xor(sum, 32); sq += __shfl_xor(sq, 32);
  if (quad == 0 && cok) {
    float* st = stats + ((((unsigned)blockIdx.x * 4 + wid) & (NBUCKET - 1)) << 7);
    atomicAdd(&st[co], sum);
    atomicAdd(&st[64 + co], sq);
  }
}

// ---- dual-BN skip: out = f2bf( bf16(relu(bns(ys))) + relu(bn(y)) ) ----
template<int CO>
__global__ __launch_bounds__(256) void bn_dual(
    const unsigned short* __restrict__ y, const float* __restrict__ st,
    const float* __restrict__ g, const float* __restrict__ b, float inv_n,
    const unsigned short* __restrict__ ys, const float* __restrict__ sts,
    const float* __restrict__ gs, const float* __restrict__ bs, float inv_ns,
    unsigned short* __restrict__ out, int nout) {
  __shared__ float sA[CO], sC[CO], sAs[CO], sCs[CO];
  for (int o = threadIdx.x; o < CO; o += 256) {
    float su = 0.f, sq = 0.f, sus = 0.f, sqs = 0.f;
#pragma unroll 8
    for (int bk = 0; bk < NBUCKET; ++bk) {
      su += st[bk * 128 + o];
      sq += st[bk * 128 + 64 + o];
      sus += sts[bk * 128 + o];
      sqs += sts[bk * 128 + 64 + o];
    }
    float mu = su * inv_n;
    float var = sq * inv_n - mu * mu;
    float a = g[o] * rsqrtf(var + EPSV);
    sA[o] = a;
    sC[o] = fmaf(-mu, a, b[o]);
    float mus = sus * inv_ns;
    float vars = sqs * inv_ns - mus * mus;
    float as = gs[o] * rsqrtf(vars + EPSV);
    sAs[o] = as;
    sCs[o] = fmaf(-mus, as, bs[o]);
  }
  __syncthreads();
  long total4 = (long)nout * CO / 4;
  for (long i4 = (long)blockIdx.x * 256 + threadIdx.x; i4 < total4;
       i4 += (long)gridDim.x * 256) {
    int o = (int)((i4 * 4) % CO);
    ushort4 v = ((const ushort4*)y)[i4];
    ushort4 w = ((const ushort4*)ys)[i4];
    float vv[4] = {bf2f(v.x), bf2f(v.y), bf2f(v.z), bf2f(v.w)};
    float ww[4] = {bf2f(w.x), bf2f(w.y), bf2f(w.z), bf2f(w.w)};
    unsigned short rr[4];
#pragma unroll
    for (int j = 0; j < 4; ++j) {
      float x = fmaxf(fmaf(vv[j], sA[o + j], sC[o + j]), 0.f);
      float sk = bf2f(f2bf(fmaxf(fmaf(ww[j], sAs[o + j], sCs[o + j]), 0.f)));
      rr[j] = f2bf(x + sk);
    }
    ushort4 r;
    r.x = rr[0]; r.y = rr[1]; r.z = rr[2]; r.w = rr[3];
    ((ushort4*)out)[i4] = r;
  }
}

// ---- fused tail: c0f = bf16(relu(bn0(y0))); x0 = c0f + relu(bn9(y9)); out0 = x0 @ lin_w.T ----
__global__ __launch_bounds__(256) void tail_kernel(
    const unsigned short* __restrict__ y0, const float* __restrict__ st0,
    const float* __restrict__ g0, const float* __restrict__ b0,
    const float* __restrict__ st9, const float* __restrict__ g9,
    const float* __restrict__ b9, float inv_n,
    const float* __restrict__ lin_w, const unsigned short* __restrict__ y9,
    float* __restrict__ out0, float* __restrict__ x0, int n0) {
  __shared__ float swl[64];
  __shared__ float sbn9[16], sbn0[16];
  if (threadIdx.x < 64) swl[threadIdx.x] = lin_w[threadIdx.x];
  if (threadIdx.x < 8) {
    int o = threadIdx.x;
    float su = 0.f, sq = 0.f, su0 = 0.f, sq0 = 0.f;
#pragma unroll 8
    for (int bk = 0; bk < NBUCKET; ++bk) {
      su += st9[bk * 128 + o];
      sq += st9[bk * 128 + 64 + o];
      su0 += st0[bk * 128 + o];
      sq0 += st0[bk * 128 + 64 + o];
    }
    float mu = su * inv_n;
    float var = sq * inv_n - mu * mu;
    float a = g9[o] * rsqrtf(var + EPSV);
    sbn9[o] = a;
    sbn9[8 + o] = fmaf(-mu, a, b9[o]);
    float mu0 = su0 * inv_n;
    float var0 = sq0 * inv_n - mu0 * mu0;
    float a0 = g0[o] * rsqrtf(var0 + EPSV);
    sbn0[o] = a0;
    sbn0[8 + o] = fmaf(-mu0, a0, b0[o]);
  }
  __syncthreads();
  for (int n = blockIdx.x * 256 + (int)threadIdx.x; n < n0; n += gridDim.x * 256) {
    const ushort4* pr = (const ushort4*)(y9 + (long)n * 8);
    ushort4 r0 = pr[0], r1 = pr[1];
    unsigned short rw[8] = {r0.x, r0.y, r0.z, r0.w, r1.x, r1.y, r1.z, r1.w};
    const ushort4* pc = (const ushort4*)(y0 + (long)n * 8);
    ushort4 c0 = pc[0], c1 = pc[1];
    unsigned short cs[8] = {c0.x, c0.y, c0.z, c0.w, c1.x, c1.y, c1.z, c1.w};
    float xv[8];
#pragma unroll
    for (int c = 0; c < 8; ++c) {
      float c0f = bf2f(f2bf(fmaxf(fmaf(bf2f(cs[c]), sbn0[c], sbn0[8 + c]), 0.f)));
      xv[c] = c0f + fmaxf(fmaf(bf2f(rw[c]), sbn9[c], sbn9[8 + c]), 0.f);
    }
    *(float4*)(x0 + (long)n * 8) = make_float4(xv[0], xv[1], xv[2], xv[3]);
    *(float4*)(x0 + (long)n * 8 + 4) = make_float4(xv[4], xv[5], xv[6], xv[7]);
    float ov[8];
#pragma unroll
    for (int j = 0; j < 8; ++j) {
      float s = 0.f;
#pragma unroll
      for (int c = 0; c < 8; ++c) s = fmaf(xv[c], swl[j * 8 + c], s);
      ov[j] = s;
    }
    *(float4*)(out0 + (long)n * 8) = make_float4(ov[0], ov[1], ov[2], ov[3]);
    *(float4*)(out0 + (long)n * 8 + 4) = make_float4(ov[4], ov[5], ov[6], ov[7]);
  }
}

extern "C" void kernel_launch(void* const* d_in, const int* in_sizes, int n_in,
                              void* d_out, int out_size, void* d_ws, size_t ws_size,
                              hipStream_t stream) {
  const float* feats = (const float*)d_in[0];
  const int* nbr0    = (const int*)d_in[1];
  const int* nbr_d01 = (const int*)d_in[2];
  const int* nbr1    = (const int*)d_in[3];
  const int* nbr_d12 = (const int*)d_in[4];
  const int* nbr2    = (const int*)d_in[5];
  const int* nbr_d23 = (const int*)d_in[6];
  const int* nbr3    = (const int*)d_in[7];
  const int* nbr_u32 = (const int*)d_in[8];
  const int* nbr_u21 = (const int*)d_in[9];
  const int* nbr_u10 = (const int*)d_in[10];
  const float* w[10];
  const float* g[10];
  const float* b[10];
  for (int i = 0; i < 10; ++i) {
    w[i] = (const float*)d_in[11 + 3 * i];
    g[i] = (const float*)d_in[12 + 3 * i];
    b[i] = (const float*)d_in[13 + 3 * i];
  }
  const float* lin_w = (const float*)d_in[41];

  const int N0 = in_sizes[0] / 16;
  const int N1 = in_sizes[2] / 27;
  const int N2 = in_sizes[4] / 27;
  const int N3 = in_sizes[6] / 27;
  const float i0 = 1.f / N0, i1 = 1.f / N1, i2 = 1.f / N2, i3 = 1.f / N3;

  static const int CIv[10] = {16, 8, 16, 16, 32, 32, 64, 64, 32, 16};
  static const int COv[10] = {8, 16, 16, 32, 32, 64, 64, 32, 16, 8};

  // ---- workspace layout ----
  float* stats = (float*)d_ws;  // 10 x NBUCKET x 128 floats
  unsigned short* u = (unsigned short*)(stats + 10 * NBUCKET * 128);

  unsigned short* wt[10];
  int wcum[11];
  wcum[0] = 0;
  for (int i = 0; i < 10; ++i) {
    wt[i] = u;
    int sz = 27 * CIv[i] * COv[i];
    u += sz;
    wcum[i + 1] = wcum[i] + sz;
  }
  unsigned short* featsb = u; u += (size_t)N0 * 16;
  unsigned short* y0 = u; u += (size_t)N0 * 8;    // raw conv outputs (persist)
  unsigned short* y1 = u; u += (size_t)N1 * 16;
  unsigned short* y2 = u; u += (size_t)N1 * 16;
  unsigned short* y3 = u; u += (size_t)N2 * 32;
  unsigned short* y4 = u; u += (size_t)N2 * 32;
  unsigned short* y5 = u; u += (size_t)N3 * 64;
  unsigned short* y6 = u; u += (size_t)N3 * 64;
  unsigned short* y7 = u; u += (size_t)N2 * 32;
  unsigned short* y8 = u; u += (size_t)N1 * 16;
  unsigned short* y9 = u; u += (size_t)N0 * 8;
  unsigned short* t5 = u; u += (size_t)N2 * 32;   // x2 (bn_dual output)
  unsigned short* t6 = u; u += (size_t)N1 * 16;   // x1 (bn_dual output)
  float* out0 = (float*)d_out;
  float* x0 = (float*)d_out + (size_t)N0 * 8;

  float* s[10];
  for (int i = 0; i < 10; ++i) s[i] = stats + i * NBUCKET * 128;

  // ---- prep ----
  PrepArgs pa;
  for (int i = 0; i < 10; ++i) {
    pa.w[i] = w[i]; pa.wt[i] = wt[i];
    pa.ci[i] = CIv[i]; pa.co[i] = COv[i];
    pa.wcum[i] = wcum[i];
  }
  pa.wcum[10] = wcum[10];
  pa.feats = feats; pa.featsb = featsb;
  pa.nfeat4 = N0 * 16 / 4;
  pa.stats = stats;
  long prep_total = (10 * NBUCKET * 128 / 4) + pa.nfeat4 + wcum[10];
  prep_kernel<<<imin((int)((prep_total + 255) / 256), 2048), 256, 0, stream>>>(pa, prep_total);

  auto bgrid = [](long nout, int co) {
    return imin((int)((nout * co / 4 + 255) / 256), 1024);
  };
  auto cgrid = [](int ntiles) { return imin(ntiles, 2048); };
  int tb0 = cdiv(N0, 64), tb1 = cdiv(N1, 64), tb2 = cdiv(N2, 64), tb3 = cdiv(N3, 64);

  // conv0: 16->8 @ N0 (plain input)
  conv_mfma<16, 8, false, 4><<<dim3(cgrid(tb0), 1), 256, 0, stream>>>(
      featsb, nbr0, wt[0], y0, s[0], nullptr, nullptr, nullptr, 0.f, N0, tb0);
  // conv1: 8->16 down to N1, input = bn0(y0) fused
  conv_mfma<8, 16, true, 4><<<dim3(cgrid(tb1), 1), 256, 0, stream>>>(
      y0, nbr_d01, wt[1], y1, s[1], s[0], g[0], b[0], i0, N1, tb1);
  // conv2: 16->16 @ N1, input = bn1(y1) fused
  conv_mfma<16, 16, true, 4><<<dim3(cgrid(tb1), 1), 256, 0, stream>>>(
      y1, nbr1, wt[2], y2, s[2], s[1], g[1], b[1], i1, N1, tb1);
  // conv3: 16->32 down to N2, input = bn2(y2) fused
  conv_mfma<16, 32, true, 4><<<dim3(cgrid(tb2), 2), 256, 0, stream>>>(
      y2, nbr_d12, wt[3], y3, s[3], s[2], g[2], b[2], i1, N2, tb2);
  // conv4: 32->32 @ N2, input = bn3(y3) fused
  conv_mfma<32, 32, true, 3><<<dim3(cgrid(tb2), 2), 256, 0, stream>>>(
      y3, nbr2, wt[4], y4, s[4], s[3], g[3], b[3], i2, N2, tb2);
  // conv5: 32->64 down to N3, input = bn4(y4) fused
  conv_mfma<32, 64, true, 3><<<dim3(cgrid(tb3), 4), 256, 0, stream>>>(
      y4, nbr_d23, wt[5], y5, s[5], s[4], g[4], b[4], i2, N3, tb3);
  // conv6: 64->64 @ N3, input = bn5(y5) fused
  conv_mfma<64, 64, true, 2><<<dim3(cgrid(tb3), 4), 256, 0, stream>>>(
      y5, nbr3, wt[6], y6, s[6], s[5], g[5], b[5], i3, N3, tb3);
  // conv7: 64->32 up to N2, input = bn6(y6) fused
  conv_mfma<64, 32, true, 2><<<dim3(cgrid(tb2), 2), 256, 0, stream>>>(
      y6, nbr_u32, wt[7], y7, s[7], s[6], g[6], b[6], i3, N2, tb2);
  // x2 = bn4(y4)-skip + relu(bn7(y7))
  bn_dual<32><<<bgrid(N2, 32), 256, 0, stream>>>(
      y7, s[7], g[7], b[7], i2, y4, s[4], g[4], b[4], i2, t5, N2);
  // conv8: 32->16 up to N1 (plain input t5)
  conv_mfma<32, 16, false, 3><<<dim3(cgrid(tb1), 1), 256, 0, stream>>>(
      t5, nbr_u21, wt[8], y8, s[8], nullptr, nullptr, nullptr, 0.f, N1, tb1);
  // x1 = bn2(y2)-skip + relu(bn8(y8))
  bn_dual<16><<<bgrid(N1, 16), 256, 0, stream>>>(
      y8, s[8], g[8], b[8], i1, y2, s[2], g[2], b[2], i1, t6, N1);
  // conv9: 16->8 up to N0 (plain input t6)
  conv_mfma<16, 8, false, 4><<<dim3(cgrid(tb0), 1), 256, 0, stream>>>(
      t6, nbr_u10, wt[9], y9, s[9], nullptr, nullptr, nullptr, 0.f, N0, tb0);
  // tail: c0f = bn0(y0); x0 = c0f + relu(bn9(y9)); out0 = x0 @ lin_w.T
  tail_kernel<<<imin(cdiv(N0, 256), 1024), 256, 0, stream>>>(
      y0, s[0], g[0], b[0], s[9], g[9], b[9], i0, lin_w, y9, out0, x0, N0);
}

// Round 4
// 430.414 us; speedup vs baseline: 4.2573x; 1.1032x over previous
//
#include <hip/hip_runtime.h>

#define EPSV 1e-5f
#define NBUCKET 64

typedef __attribute__((ext_vector_type(8))) short short8;
typedef __attribute__((ext_vector_type(4))) float float4v;

static inline int cdiv(int a, int b) { return (a + b - 1) / b; }
static inline int imin(int a, int b) { return a < b ? a : b; }

__device__ inline unsigned short f2bf(float x) {
  unsigned u = __float_as_uint(x);
  return (unsigned short)((u + 0x7FFFu + ((u >> 16) & 1u)) >> 16);
}
__device__ inline float bf2f(unsigned short u) {
  return __uint_as_float(((unsigned)u) << 16);
}

struct PrepArgs {
  const float* w[10];
  unsigned short* wt[10];
  int ci[10];
  int co[10];
  int wcum[11];
  const float* feats;
  unsigned short* featsb;
  int nfeat4;
  float* stats;
};

// grid-stride: zero stats + feats fp32->bf16 + weights fp32->bf16 transposed [27][CO][CI]
__global__ __launch_bounds__(256) void prep_kernel(PrepArgs p, long total) {
  const int nstat4 = 10 * NBUCKET * 128 / 4;
  for (long tid0 = (long)blockIdx.x * 256 + threadIdx.x; tid0 < total;
       tid0 += (long)gridDim.x * 256) {
    long tid = tid0;
    if (tid < nstat4) {
      ((float4*)p.stats)[tid] = make_float4(0.f, 0.f, 0.f, 0.f);
      continue;
    }
    tid -= nstat4;
    if (tid < p.nfeat4) {
      float4 v = ((const float4*)p.feats)[tid];
      ushort4 r;
      r.x = f2bf(v.x); r.y = f2bf(v.y); r.z = f2bf(v.z); r.w = f2bf(v.w);
      ((ushort4*)p.featsb)[tid] = r;
      continue;
    }
    tid -= p.nfeat4;
    if (tid >= p.wcum[10]) continue;
    int i = 0;
    while (tid >= p.wcum[i + 1]) ++i;
    int e = (int)(tid - p.wcum[i]);
    int ci = p.ci[i], co = p.co[i];
    int k = e / (ci * co);
    int r = e - k * (ci * co);
    int o = r / ci;
    int c = r - o * ci;
    p.wt[i][((long)k * co + o) * ci + c] = f2bf(p.w[i][((long)k * ci + c) * co + o]);
  }
}

// ================= MFMA gather-GEMM conv, XCD-chunked tile ownership =================
// Block = 4 waves; wave handles one 16-row MFMA tile per 64-row block-tile.
// gridDim.x is a multiple of 8; block b belongs to XCD (b&7) (round-robin dispatch),
// XCD x owns the contiguous tile range [x*ntiles/8, ...), blocks stride within it.
// Spatially adjacent tiles gather overlapping feature rows -> local-L2 hits instead
// of cross-die traffic. gridDim.y (CO slices) shares x -> same tiles, same XCD.
// nbr indices staged cooperatively through LDS (coalesced int4 -> ds_read).
// Weight slice [27][16][CI] staged in LDS once per block.
template<int CI, int CO, int MINW>
__global__ __launch_bounds__(256, MINW) void conv_mfma(
    const unsigned short* __restrict__ f, const int* __restrict__ nbr,
    const unsigned short* __restrict__ wt, unsigned short* __restrict__ y,
    float* __restrict__ stats, int nout, int ntiles) {
  constexpr int NCHUNK = (CI == 8) ? 7 : (CI == 16) ? 14 : (CI == 32) ? 27 : 54;
  // LDS B row stride (in shorts): padded to 16B multiple with odd 16B count for
  // bank spread; CI=64 uses linear stride 128B + XOR swizzle.
  constexpr int CIP = (CI == 64) ? 64 : (CI == 32) ? 40 : 24;

  __shared__ int nbrT[64 * 27];
  __shared__ unsigned short Bs[27 * 16 * CIP];

  const int tid = threadIdx.x;
  const int lane = tid & 63;
  const int wid = tid >> 6;
  const int m = lane & 15;
  const int quad = lane >> 4;
  const int cbase = blockIdx.y * 16;
  const int co = cbase + m;
  const bool cok = co < CO;

  auto tapof = [&](int c) -> int {
    if constexpr (CI == 8) return c * 4 + quad;
    else if constexpr (CI == 16) return c * 2 + (quad >> 1);
    else if constexpr (CI == 32) return c;
    else return c >> 1;
  };
  auto cioof = [&](int c) -> int {
    if constexpr (CI == 8) return 0;
    else if constexpr (CI == 16) return (quad & 1) * 8;
    else if constexpr (CI == 32) return quad * 8;
    else return ((c & 1) << 5) + quad * 8;
  };
  // LDS B address (short index) for [tap][mm][cio]
  auto baddr = [&](int tap, int mm, int cio) -> int {
    if constexpr (CI == 64) {
      int byt = (tap * 16 + mm) * 128 + cio * 2;
      byt ^= (mm & 7) << 4;  // XOR-swizzle 16B slot within the 128B row
      return byt >> 1;
    } else {
      return (tap * 16 + mm) * CIP + cio;
    }
  };

  // ---- cooperative weight-slice load into LDS (once per block) ----
  {
    constexpr int NC8 = CI / 8;
    for (int t = tid; t < 27 * 16 * NC8; t += 256) {
      int tap = t / (16 * NC8);
      int r = t - tap * (16 * NC8);
      int mo = r / NC8;
      int c8 = (r - mo * NC8) * 8;
      short8 v;
#pragma unroll
      for (int q = 0; q < 8; ++q) v[q] = 0;
      int c = cbase + mo;
      if (c < CO) v = *(const short8*)(wt + ((long)tap * CO + c) * CI + c8);
      *(short8*)&Bs[baddr(tap, mo, c8)] = v;
    }
  }
  // first __syncthreads inside the tile loop orders Bs fill before any read

  // ---- XCD-chunked tile range ----
  const int nb8 = (int)gridDim.x >> 3;      // blocks per XCD (gridDim.x % 8 == 0)
  const int xcd = (int)blockIdx.x & 7;
  const int slot = (int)blockIdx.x >> 3;
  const int tq8 = ntiles >> 3, tr8 = ntiles & 7;
  const int t0 = xcd * tq8 + (xcd < tr8 ? xcd : tr8);
  const int tcnt = tq8 + (xcd < tr8 ? 1 : 0);

  float sum = 0.f, sq = 0.f;

  for (int ti = slot; ti < tcnt; ti += nb8) {
    const int tile = t0 + ti;
    const int rowb0 = tile * 64;
    // ---- cooperative nbr stage: contiguous int4 loads ----
    {
      const long base = (long)rowb0 * 27;
      const long lim = (long)nout * 27;
      for (int j = tid; j < 432; j += 256) {  // 432 int4 = 1728 ints
        long g = base + j * 4;
        int4 v;
        if (g + 4 <= lim) {
          v = *(const int4*)(nbr + g);
        } else {
          v.x = (g + 0 < lim) ? nbr[g + 0] : -1;
          v.y = (g + 1 < lim) ? nbr[g + 1] : -1;
          v.z = (g + 2 < lim) ? nbr[g + 2] : -1;
          v.w = (g + 3 < lim) ? nbr[g + 3] : -1;
        }
        *(int4*)&nbrT[j * 4] = v;
      }
    }
    __syncthreads();

    const int rowb = rowb0 + wid * 16;
    const int lrow = (wid * 16 + m) * 27;
    float4v acc = {0.f, 0.f, 0.f, 0.f};

    if constexpr (CI <= 16) {
      int idxs[NCHUNK];
#pragma unroll
      for (int c = 0; c < NCHUNK; ++c) {
        int tap = tapof(c);
        idxs[c] = (tap < 27) ? nbrT[lrow + tap] : -1;
      }
      short8 A[NCHUNK];
#pragma unroll
      for (int c = 0; c < NCHUNK; ++c) {
        short8 a;
#pragma unroll
        for (int q = 0; q < 8; ++q) a[q] = 0;
        if (idxs[c] >= 0) a = *(const short8*)(f + (long)idxs[c] * CI + cioof(c));
        A[c] = a;
      }
#pragma unroll
      for (int c = 0; c < NCHUNK; ++c) {
        int tap = tapof(c);
        int tapc = tap < 27 ? tap : 26;  // A=0 masks the clamped B
        short8 bf = *(const short8*)&Bs[baddr(tapc, m, cioof(c))];
        acc = __builtin_amdgcn_mfma_f32_16x16x32_bf16(A[c], bf, acc, 0, 0, 0);
      }
    } else {
      constexpr int G = 9;
      constexpr int NG = NCHUNK / G;
      short8 A[2][G];
      auto load_group = [&](int g, int bi) {
#pragma unroll
        for (int j = 0; j < G; ++j) {
          const int c = g * G + j;
          const int tap = tapof(c);
          int idx = nbrT[lrow + tap];
          short8 a;
#pragma unroll
          for (int q = 0; q < 8; ++q) a[q] = 0;
          if (idx >= 0) a = *(const short8*)(f + (long)idx * CI + cioof(c));
          A[bi][j] = a;
        }
      };
      load_group(0, 0);
#pragma unroll
      for (int g = 0; g < NG; ++g) {
        const int cur = g & 1;
        if (g + 1 < NG) load_group(g + 1, cur ^ 1);
#pragma unroll
        for (int j = 0; j < G; ++j) {
          const int c = g * G + j;
          short8 bf = *(const short8*)&Bs[baddr(tapof(c), m, cioof(c))];
          acc = __builtin_amdgcn_mfma_f32_16x16x32_bf16(A[cur][j], bf, acc, 0, 0, 0);
        }
      }
    }

#pragma unroll
    for (int r = 0; r < 4; ++r) {
      float v = acc[r];
      int orow = rowb + quad * 4 + r;
      if (cok && orow < nout) y[(long)orow * CO + co] = f2bf(v);
      sum += v;
      sq = fmaf(v, v, sq);
    }
    __syncthreads();  // nbrT reused next iteration
  }

  // one atomic pair per wave
  sum += __shfl_xor(sum, 16); sq += __shfl_xor(sq, 16);
  sum += __shfl_xor(sum, 32); sq += __shfl_xor(sq, 32);
  if (quad == 0 && cok) {
    float* st = stats + ((((unsigned)blockIdx.x * 4 + wid) & (NBUCKET - 1)) << 7);
    atomicAdd(&st[co], sum);
    atomicAdd(&st[64 + co], sq);
  }
}

// ---- BN+ReLU (+bf16 skip), bf16 y -> bf16 feature map, grid-stride ----
template<int CO>
__global__ __launch_bounds__(256) void bn_relu_bf16(
    const unsigned short* __restrict__ y, const float* __restrict__ stats,
    const float* __restrict__ g, const float* __restrict__ b,
    const unsigned short* __restrict__ skip, unsigned short* __restrict__ out,
    int nout, float inv_n) {
  __shared__ float sA[CO], sC[CO];
  if ((int)threadIdx.x < CO) {
    int o = threadIdx.x;
    float su = 0.f, sq = 0.f;
#pragma unroll 8
    for (int bk = 0; bk < NBUCKET; ++bk) {
      su += stats[bk * 128 + o];
      sq += stats[bk * 128 + 64 + o];
    }
    float mu = su * inv_n;
    float var = sq * inv_n - mu * mu;
    float a = g[o] * rsqrtf(var + EPSV);
    sA[o] = a;
    sC[o] = fmaf(-mu, a, b[o]);
  }
  __syncthreads();
  long total4 = (long)nout * CO / 4;
  for (long i4 = (long)blockIdx.x * 256 + threadIdx.x; i4 < total4;
       i4 += (long)gridDim.x * 256) {
    int o = (int)((i4 * 4) % CO);
    ushort4 v = ((const ushort4*)y)[i4];
    float vv[4] = {bf2f(v.x), bf2f(v.y), bf2f(v.z), bf2f(v.w)};
    unsigned short rr[4];
#pragma unroll
    for (int j = 0; j < 4; ++j) {
      float x = fmaxf(fmaf(vv[j], sA[o + j], sC[o + j]), 0.f);
      if (skip) x += bf2f(skip[i4 * 4 + j]);
      rr[j] = f2bf(x);
    }
    ushort4 r;
    r.x = rr[0]; r.y = rr[1]; r.z = rr[2]; r.w = rr[3];
    ((ushort4*)out)[i4] = r;
  }
}

// ---- fused tail: x0 = c0f + relu(bn(y9)); out0 = x0 @ lin_w.T, grid-stride ----
__global__ __launch_bounds__(256) void tail_kernel(
    const unsigned short* __restrict__ c0f, const float* __restrict__ st9,
    const float* __restrict__ g9, const float* __restrict__ b9, float inv_n,
    const float* __restrict__ lin_w, const unsigned short* __restrict__ y9,
    float* __restrict__ out0, float* __restrict__ x0, int n0) {
  __shared__ float swl[64];
  __shared__ float sbn[16];
  if (threadIdx.x < 64) swl[threadIdx.x] = lin_w[threadIdx.x];
  if (threadIdx.x < 8) {
    int o = threadIdx.x;
    float su = 0.f, sq = 0.f;
#pragma unroll 8
    for (int bk = 0; bk < NBUCKET; ++bk) {
      su += st9[bk * 128 + o];
      sq += st9[bk * 128 + 64 + o];
    }
    float mu = su * inv_n;
    float var = sq * inv_n - mu * mu;
    float a = g9[o] * rsqrtf(var + EPSV);
    sbn[o] = a;
    sbn[8 + o] = fmaf(-mu, a, b9[o]);
  }
  __syncthreads();
  for (int n = blockIdx.x * 256 + (int)threadIdx.x; n < n0; n += gridDim.x * 256) {
    const ushort4* pr = (const ushort4*)(y9 + (long)n * 8);
    ushort4 r0 = pr[0], r1 = pr[1];
    unsigned short rw[8] = {r0.x, r0.y, r0.z, r0.w, r1.x, r1.y, r1.z, r1.w};
    const ushort4* pc = (const ushort4*)(c0f + (long)n * 8);
    ushort4 c0 = pc[0], c1 = pc[1];
    unsigned short cs[8] = {c0.x, c0.y, c0.z, c0.w, c1.x, c1.y, c1.z, c1.w};
    float xv[8];
#pragma unroll
    for (int c = 0; c < 8; ++c)
      xv[c] = bf2f(cs[c]) + fmaxf(fmaf(bf2f(rw[c]), sbn[c], sbn[8 + c]), 0.f);
    *(float4*)(x0 + (long)n * 8) = make_float4(xv[0], xv[1], xv[2], xv[3]);
    *(float4*)(x0 + (long)n * 8 + 4) = make_float4(xv[4], xv[5], xv[6], xv[7]);
    float ov[8];
#pragma unroll
    for (int j = 0; j < 8; ++j) {
      float s = 0.f;
#pragma unroll
      for (int c = 0; c < 8; ++c) s = fmaf(xv[c], swl[j * 8 + c], s);
      ov[j] = s;
    }
    *(float4*)(out0 + (long)n * 8) = make_float4(ov[0], ov[1], ov[2], ov[3]);
    *(float4*)(out0 + (long)n * 8 + 4) = make_float4(ov[4], ov[5], ov[6], ov[7]);
  }
}

extern "C" void kernel_launch(void* const* d_in, const int* in_sizes, int n_in,
                              void* d_out, int out_size, void* d_ws, size_t ws_size,
                              hipStream_t stream) {
  const float* feats   = (const float*)d_in[0];
  const int* nbr0      = (const int*)d_in[1];
  const int* nbr_d01   = (const int*)d_in[2];
  const int* nbr1      = (const int*)d_in[3];
  const int* nbr_d12   = (const int*)d_in[4];
  const int* nbr2      = (const int*)d_in[5];
  const int* nbr_d23   = (const int*)d_in[6];
  const int* nbr3      = (const int*)d_in[7];
  const int* nbr_u32   = (const int*)d_in[8];
  const int* nbr_u21   = (const int*)d_in[9];
  const int* nbr_u10   = (const int*)d_in[10];
  const float* w[10];
  const float* g[10];
  const float* b[10];
  for (int i = 0; i < 10; ++i) {
    w[i] = (const float*)d_in[11 + 3 * i];
    g[i] = (const float*)d_in[12 + 3 * i];
    b[i] = (const float*)d_in[13 + 3 * i];
  }
  const float* lin_w = (const float*)d_in[41];

  const int N0 = in_sizes[0] / 16;
  const int N1 = in_sizes[2] / 27;
  const int N2 = in_sizes[4] / 27;
  const int N3 = in_sizes[6] / 27;
  const float i0 = 1.f / N0, i1 = 1.f / N1, i2 = 1.f / N2, i3 = 1.f / N3;

  static const int CIv[10] = {16, 8, 16, 16, 32, 32, 64, 64, 32, 16};
  static const int COv[10] = {8, 16, 16, 32, 32, 64, 64, 32, 16, 8};

  // ---- workspace: fp32 stats region, then bf16 (ushort) region ----
  float* stats = (float*)d_ws;                       // 10 x NBUCKET x 128 floats
  unsigned short* u = (unsigned short*)(stats + 10 * NBUCKET * 128);

  unsigned short* yraw = u; u += (size_t)N1 * 32;    // bf16 y scratch

  unsigned short* wt[10];
  int wcum[11];
  wcum[0] = 0;
  for (int i = 0; i < 10; ++i) {
    wt[i] = u;
    int sz = 27 * CIv[i] * COv[i];
    u += sz;
    wcum[i + 1] = wcum[i] + sz;
  }
  unsigned short* featsb = u; u += (size_t)N0 * 16;
  unsigned short* c0f = u;    u += (size_t)N0 * 8;
  unsigned short* t1  = u;    u += (size_t)N1 * 16;
  unsigned short* c2f = u;    u += (size_t)N1 * 16;
  unsigned short* t2  = u;    u += (size_t)N2 * 32;
  unsigned short* c4f = u;    u += (size_t)N2 * 32;
  unsigned short* t3  = u;    u += (size_t)N3 * 64;
  unsigned short* t4  = u;    u += (size_t)N3 * 64;
  unsigned short* t5  = t2;   // reuse
  unsigned short* t6  = t1;   // reuse
  float* out0 = (float*)d_out;
  float* x0   = (float*)d_out + (size_t)N0 * 8;

  float* s[10];
  for (int i = 0; i < 10; ++i) s[i] = stats + i * NBUCKET * 128;

  // ---- prep (grid-stride) ----
  PrepArgs pa;
  for (int i = 0; i < 10; ++i) {
    pa.w[i] = w[i]; pa.wt[i] = wt[i];
    pa.ci[i] = CIv[i]; pa.co[i] = COv[i];
    pa.wcum[i] = wcum[i];
  }
  pa.wcum[10] = wcum[10];
  pa.feats = feats; pa.featsb = featsb;
  pa.nfeat4 = N0 * 16 / 4;
  pa.stats = stats;
  long prep_total = (10 * NBUCKET * 128 / 4) + pa.nfeat4 + wcum[10];
  prep_kernel<<<imin((int)((prep_total + 255) / 256), 2048), 256, 0, stream>>>(pa, prep_total);

  auto bgrid = [](long nout, int co) {
    return imin((int)((nout * co / 4 + 255) / 256), 1024);
  };
  // grid multiple of 8 so block->XCD chunking is bijective
  auto cgrid = [](int ntiles) {
    int g = (ntiles + 7) & ~7;
    if (g < 8) g = 8;
    return imin(g, 2048);
  };

  int tb0 = cdiv(N0, 64), tb1 = cdiv(N1, 64), tb2 = cdiv(N2, 64), tb3 = cdiv(N3, 64);

  // conv0: 16->8 @ N0
  conv_mfma<16, 8, 4><<<dim3(cgrid(tb0), 1), 256, 0, stream>>>(featsb, nbr0, wt[0], yraw, s[0], N0, tb0);
  bn_relu_bf16<8><<<bgrid(N0, 8), 256, 0, stream>>>(yraw, s[0], g[0], b[0], nullptr, c0f, N0, i0);

  // conv1: 8->16 down to N1
  conv_mfma<8, 16, 4><<<dim3(cgrid(tb1), 1), 256, 0, stream>>>(c0f, nbr_d01, wt[1], yraw, s[1], N1, tb1);
  bn_relu_bf16<16><<<bgrid(N1, 16), 256, 0, stream>>>(yraw, s[1], g[1], b[1], nullptr, t1, N1, i1);

  // conv2: 16->16 @ N1
  conv_mfma<16, 16, 4><<<dim3(cgrid(tb1), 1), 256, 0, stream>>>(t1, nbr1, wt[2], yraw, s[2], N1, tb1);
  bn_relu_bf16<16><<<bgrid(N1, 16), 256, 0, stream>>>(yraw, s[2], g[2], b[2], nullptr, c2f, N1, i1);

  // conv3: 16->32 down to N2
  conv_mfma<16, 32, 4><<<dim3(cgrid(tb2), 2), 256, 0, stream>>>(c2f, nbr_d12, wt[3], yraw, s[3], N2, tb2);
  bn_relu_bf16<32><<<bgrid(N2, 32), 256, 0, stream>>>(yraw, s[3], g[3], b[3], nullptr, t2, N2, i2);

  // conv4: 32->32 @ N2
  conv_mfma<32, 32, 3><<<dim3(cgrid(tb2), 2), 256, 0, stream>>>(t2, nbr2, wt[4], yraw, s[4], N2, tb2);
  bn_relu_bf16<32><<<bgrid(N2, 32), 256, 0, stream>>>(yraw, s[4], g[4], b[4], nullptr, c4f, N2, i2);

  // conv5: 32->64 down to N3
  conv_mfma<32, 64, 3><<<dim3(cgrid(tb3), 4), 256, 0, stream>>>(c4f, nbr_d23, wt[5], yraw, s[5], N3, tb3);
  bn_relu_bf16<64><<<bgrid(N3, 64), 256, 0, stream>>>(yraw, s[5], g[5], b[5], nullptr, t3, N3, i3);

  // conv6: 64->64 @ N3
  conv_mfma<64, 64, 2><<<dim3(cgrid(tb3), 4), 256, 0, stream>>>(t3, nbr3, wt[6], yraw, s[6], N3, tb3);
  bn_relu_bf16<64><<<bgrid(N3, 64), 256, 0, stream>>>(yraw, s[6], g[6], b[6], nullptr, t4, N3, i3);

  // conv7: 64->32 up to N2; x2 = c4f + relu(bn(y7))
  conv_mfma<64, 32, 2><<<dim3(cgrid(tb2), 2), 256, 0, stream>>>(t4, nbr_u32, wt[7], yraw, s[7], N2, tb2);
  bn_relu_bf16<32><<<bgrid(N2, 32), 256, 0, stream>>>(yraw, s[7], g[7], b[7], c4f, t5, N2, i2);

  // conv8: 32->16 up to N1; x1 = c2f + relu(bn(y8))
  conv_mfma<32, 16, 3><<<dim3(cgrid(tb1), 1), 256, 0, stream>>>(t5, nbr_u21, wt[8], yraw, s[8], N1, tb1);
  bn_relu_bf16<16><<<bgrid(N1, 16), 256, 0, stream>>>(yraw, s[8], g[8], b[8], c2f, t6, N1, i1);

  // conv9: 16->8 up to N0; y9 bf16 in yraw
  conv_mfma<16, 8, 4><<<dim3(cgrid(tb0), 1), 256, 0, stream>>>(t6, nbr_u10, wt[9], yraw, s[9], N0, tb0);

  // tail: x0 = c0f + relu(bn(y9)); out0 = x0 @ lin_w.T
  tail_kernel<<<imin(cdiv(N0, 256), 1024), 256, 0, stream>>>(
      c0f, s[9], g[9], b[9], i0, lin_w, yraw, out0, x0, N0);
}

// Round 5
// 428.229 us; speedup vs baseline: 4.2790x; 1.0051x over previous
//
#include <hip/hip_runtime.h>

#define EPSV 1e-5f
#define NBUCKET 64

typedef __attribute__((ext_vector_type(8))) short short8;
typedef __attribute__((ext_vector_type(4))) float float4v;

static inline int cdiv(int a, int b) { return (a + b - 1) / b; }
static inline int imin(int a, int b) { return a < b ? a : b; }

__device__ inline unsigned short f2bf(float x) {
  unsigned u = __float_as_uint(x);
  return (unsigned short)((u + 0x7FFFu + ((u >> 16) & 1u)) >> 16);
}
__device__ inline float bf2f(unsigned short u) {
  return __uint_as_float(((unsigned)u) << 16);
}

struct PrepArgs {
  const float* w[10];
  unsigned short* wt[10];
  int ci[10];
  int co[10];
  int wcum[11];
  const float* feats;
  unsigned short* featsb;
  int nfeat4;
  float* stats;
};

// grid-stride: zero stats + feats fp32->bf16 + weights fp32->bf16 transposed [27][CO][CI]
__global__ __launch_bounds__(256) void prep_kernel(PrepArgs p, long total) {
  const int nstat4 = 10 * NBUCKET * 128 / 4;
  for (long tid0 = (long)blockIdx.x * 256 + threadIdx.x; tid0 < total;
       tid0 += (long)gridDim.x * 256) {
    long tid = tid0;
    if (tid < nstat4) {
      ((float4*)p.stats)[tid] = make_float4(0.f, 0.f, 0.f, 0.f);
      continue;
    }
    tid -= nstat4;
    if (tid < p.nfeat4) {
      float4 v = ((const float4*)p.feats)[tid];
      ushort4 r;
      r.x = f2bf(v.x); r.y = f2bf(v.y); r.z = f2bf(v.z); r.w = f2bf(v.w);
      ((ushort4*)p.featsb)[tid] = r;
      continue;
    }
    tid -= p.nfeat4;
    if (tid >= p.wcum[10]) continue;
    int i = 0;
    while (tid >= p.wcum[i + 1]) ++i;
    int e = (int)(tid - p.wcum[i]);
    int ci = p.ci[i], co = p.co[i];
    int k = e / (ci * co);
    int r = e - k * (ci * co);
    int o = r / ci;
    int c = r - o * ci;
    p.wt[i][((long)k * co + o) * ci + c] = f2bf(p.w[i][((long)k * ci + c) * co + o]);
  }
}

// ================= MFMA gather-GEMM conv: ONE 64-row tile per block =================
// Block = 4 waves; wave w handles rows [tile*64 + w*16, +16). grid.x = ntiles exactly
// (no tile loop, single __syncthreads per block) -> block churn pipelines the
// per-tile latency chain across 6-9 resident blocks/CU.
// LDS lean: Bs rows = min(CO,16) (CO=8 kernels drop to 17.3 KB total), CI=8 stride 12.
// nbr indices staged cooperatively (coalesced int4); weight slice staged per block.
template<int CI, int CO, int MINW>
__global__ __launch_bounds__(256, MINW) void conv_mfma(
    const unsigned short* __restrict__ f, const int* __restrict__ nbr,
    const unsigned short* __restrict__ wt, unsigned short* __restrict__ y,
    float* __restrict__ stats, int nout) {
  constexpr int NCHUNK = (CI == 8) ? 7 : (CI == 16) ? 14 : (CI == 32) ? 27 : 54;
  // LDS B row stride (shorts): pad for bank spread; CI=64 linear 128B + XOR swizzle.
  constexpr int CIP = (CI == 64) ? 64 : (CI == 32) ? 40 : (CI == 16) ? 24 : 12;
  constexpr int RB = (CO < 16) ? CO : 16;  // B rows actually stored (CO=8 -> 8)

  __shared__ int nbrT[64 * 27];
  __shared__ unsigned short Bs[27 * RB * CIP];

  const int tid = threadIdx.x;
  const int lane = tid & 63;
  const int wid = tid >> 6;
  const int m = lane & 15;
  const int mm = m & (RB - 1);  // clamped B row for dead lanes (RB power of 2)
  const int quad = lane >> 4;
  const int cbase = blockIdx.y * 16;
  const int co = cbase + m;
  const bool cok = co < CO;

  auto tapof = [&](int c) -> int {
    if constexpr (CI == 8) return c * 4 + quad;
    else if constexpr (CI == 16) return c * 2 + (quad >> 1);
    else if constexpr (CI == 32) return c;
    else return c >> 1;
  };
  auto cioof = [&](int c) -> int {
    if constexpr (CI == 8) return 0;
    else if constexpr (CI == 16) return (quad & 1) * 8;
    else if constexpr (CI == 32) return quad * 8;
    else return ((c & 1) << 5) + quad * 8;
  };
  // LDS B address (short index) for [tap][row][cio]
  auto baddr = [&](int tap, int r, int cio) -> int {
    if constexpr (CI == 64) {
      int byt = (tap * 16 + r) * 128 + cio * 2;
      byt ^= (r & 7) << 4;  // XOR-swizzle 16B slot within the 128B row
      return byt >> 1;
    } else {
      return (tap * RB + r) * CIP + cio;
    }
  };

  const int tile = blockIdx.x;
  const int rowb0 = tile * 64;

  // ---- cooperative weight-slice load into LDS ----
  {
    constexpr int NC8 = CI / 8;
    for (int t = tid; t < 27 * RB * NC8; t += 256) {
      int tap = t / (RB * NC8);
      int r = t - tap * (RB * NC8);
      int mo = r / NC8;
      int c8 = (r - mo * NC8) * 8;
      short8 v;
#pragma unroll
      for (int q = 0; q < 8; ++q) v[q] = 0;
      int c = cbase + mo;
      if (c < CO) v = *(const short8*)(wt + ((long)tap * CO + c) * CI + c8);
      *(short8*)&Bs[baddr(tap, mo, c8)] = v;
    }
  }
  // ---- cooperative nbr stage: contiguous int4 loads ----
  {
    const long base = (long)rowb0 * 27;
    const long lim = (long)nout * 27;
    for (int j = tid; j < 432; j += 256) {  // 432 int4 = 1728 ints
      long g = base + j * 4;
      int4 v;
      if (g + 4 <= lim) {
        v = *(const int4*)(nbr + g);
      } else {
        v.x = (g + 0 < lim) ? nbr[g + 0] : -1;
        v.y = (g + 1 < lim) ? nbr[g + 1] : -1;
        v.z = (g + 2 < lim) ? nbr[g + 2] : -1;
        v.w = (g + 3 < lim) ? nbr[g + 3] : -1;
      }
      *(int4*)&nbrT[j * 4] = v;
    }
  }
  __syncthreads();

  const int rowb = rowb0 + wid * 16;
  const int lrow = (wid * 16 + m) * 27;
  float4v acc = {0.f, 0.f, 0.f, 0.f};

  if constexpr (CI <= 16) {
    int idxs[NCHUNK];
#pragma unroll
    for (int c = 0; c < NCHUNK; ++c) {
      int tap = tapof(c);
      idxs[c] = (tap < 27) ? nbrT[lrow + tap] : -1;
    }
    short8 A[NCHUNK];
#pragma unroll
    for (int c = 0; c < NCHUNK; ++c) {
      short8 a;
#pragma unroll
      for (int q = 0; q < 8; ++q) a[q] = 0;
      if (idxs[c] >= 0) a = *(const short8*)(f + (long)idxs[c] * CI + cioof(c));
      A[c] = a;
    }
#pragma unroll
    for (int c = 0; c < NCHUNK; ++c) {
      int tap = tapof(c);
      int tapc = tap < 27 ? tap : 26;  // A=0 masks the clamped B
      short8 bf = *(const short8*)&Bs[baddr(tapc, mm, cioof(c))];
      acc = __builtin_amdgcn_mfma_f32_16x16x32_bf16(A[c], bf, acc, 0, 0, 0);
    }
  } else {
    constexpr int G = 9;
    constexpr int NG = NCHUNK / G;
    short8 A[2][G];
    auto load_group = [&](int g, int bi) {
#pragma unroll
      for (int j = 0; j < G; ++j) {
        const int c = g * G + j;
        const int tap = tapof(c);
        int idx = nbrT[lrow + tap];
        short8 a;
#pragma unroll
        for (int q = 0; q < 8; ++q) a[q] = 0;
        if (idx >= 0) a = *(const short8*)(f + (long)idx * CI + cioof(c));
        A[bi][j] = a;
      }
    };
    load_group(0, 0);
#pragma unroll
    for (int g = 0; g < NG; ++g) {
      const int cur = g & 1;
      if (g + 1 < NG) load_group(g + 1, cur ^ 1);
#pragma unroll
      for (int j = 0; j < G; ++j) {
        const int c = g * G + j;
        short8 bf = *(const short8*)&Bs[baddr(tapof(c), mm, cioof(c))];
        acc = __builtin_amdgcn_mfma_f32_16x16x32_bf16(A[cur][j], bf, acc, 0, 0, 0);
      }
    }
  }

  float sum = 0.f, sq = 0.f;
#pragma unroll
  for (int r = 0; r < 4; ++r) {
    float v = acc[r];
    int orow = rowb + quad * 4 + r;
    if (cok && orow < nout) y[(long)orow * CO + co] = f2bf(v);
    sum += v;
    sq = fmaf(v, v, sq);
  }

  // one atomic pair per wave
  sum += __shfl_xor(sum, 16); sq += __shfl_xor(sq, 16);
  sum += __shfl_xor(sum, 32); sq += __shfl_xor(sq, 32);
  if (quad == 0 && cok) {
    float* st = stats + ((((unsigned)blockIdx.x * 4 + wid) & (NBUCKET - 1)) << 7);
    atomicAdd(&st[co], sum);
    atomicAdd(&st[64 + co], sq);
  }
}

// ---- BN+ReLU (+bf16 skip), bf16 y -> bf16 feature map, grid-stride ----
template<int CO>
__global__ __launch_bounds__(256) void bn_relu_bf16(
    const unsigned short* __restrict__ y, const float* __restrict__ stats,
    const float* __restrict__ g, const float* __restrict__ b,
    const unsigned short* __restrict__ skip, unsigned short* __restrict__ out,
    int nout, float inv_n) {
  __shared__ float sA[CO], sC[CO];
  if ((int)threadIdx.x < CO) {
    int o = threadIdx.x;
    float su = 0.f, sq = 0.f;
#pragma unroll 8
    for (int bk = 0; bk < NBUCKET; ++bk) {
      su += stats[bk * 128 + o];
      sq += stats[bk * 128 + 64 + o];
    }
    float mu = su * inv_n;
    float var = sq * inv_n - mu * mu;
    float a = g[o] * rsqrtf(var + EPSV);
    sA[o] = a;
    sC[o] = fmaf(-mu, a, b[o]);
  }
  __syncthreads();
  long total4 = (long)nout * CO / 4;
  for (long i4 = (long)blockIdx.x * 256 + threadIdx.x; i4 < total4;
       i4 += (long)gridDim.x * 256) {
    int o = (int)((i4 * 4) % CO);
    ushort4 v = ((const ushort4*)y)[i4];
    float vv[4] = {bf2f(v.x), bf2f(v.y), bf2f(v.z), bf2f(v.w)};
    unsigned short rr[4];
#pragma unroll
    for (int j = 0; j < 4; ++j) {
      float x = fmaxf(fmaf(vv[j], sA[o + j], sC[o + j]), 0.f);
      if (skip) x += bf2f(skip[i4 * 4 + j]);
      rr[j] = f2bf(x);
    }
    ushort4 r;
    r.x = rr[0]; r.y = rr[1]; r.z = rr[2]; r.w = rr[3];
    ((ushort4*)out)[i4] = r;
  }
}

// ---- fused tail: x0 = c0f + relu(bn(y9)); out0 = x0 @ lin_w.T, grid-stride ----
__global__ __launch_bounds__(256) void tail_kernel(
    const unsigned short* __restrict__ c0f, const float* __restrict__ st9,
    const float* __restrict__ g9, const float* __restrict__ b9, float inv_n,
    const float* __restrict__ lin_w, const unsigned short* __restrict__ y9,
    float* __restrict__ out0, float* __restrict__ x0, int n0) {
  __shared__ float swl[64];
  __shared__ float sbn[16];
  if (threadIdx.x < 64) swl[threadIdx.x] = lin_w[threadIdx.x];
  if (threadIdx.x < 8) {
    int o = threadIdx.x;
    float su = 0.f, sq = 0.f;
#pragma unroll 8
    for (int bk = 0; bk < NBUCKET; ++bk) {
      su += st9[bk * 128 + o];
      sq += st9[bk * 128 + 64 + o];
    }
    float mu = su * inv_n;
    float var = sq * inv_n - mu * mu;
    float a = g9[o] * rsqrtf(var + EPSV);
    sbn[o] = a;
    sbn[8 + o] = fmaf(-mu, a, b9[o]);
  }
  __syncthreads();
  for (int n = blockIdx.x * 256 + (int)threadIdx.x; n < n0; n += gridDim.x * 256) {
    const ushort4* pr = (const ushort4*)(y9 + (long)n * 8);
    ushort4 r0 = pr[0], r1 = pr[1];
    unsigned short rw[8] = {r0.x, r0.y, r0.z, r0.w, r1.x, r1.y, r1.z, r1.w};
    const ushort4* pc = (const ushort4*)(c0f + (long)n * 8);
    ushort4 c0 = pc[0], c1 = pc[1];
    unsigned short cs[8] = {c0.x, c0.y, c0.z, c0.w, c1.x, c1.y, c1.z, c1.w};
    float xv[8];
#pragma unroll
    for (int c = 0; c < 8; ++c)
      xv[c] = bf2f(cs[c]) + fmaxf(fmaf(bf2f(rw[c]), sbn[c], sbn[8 + c]), 0.f);
    *(float4*)(x0 + (long)n * 8) = make_float4(xv[0], xv[1], xv[2], xv[3]);
    *(float4*)(x0 + (long)n * 8 + 4) = make_float4(xv[4], xv[5], xv[6], xv[7]);
    float ov[8];
#pragma unroll
    for (int j = 0; j < 8; ++j) {
      float s = 0.f;
#pragma unroll
      for (int c = 0; c < 8; ++c) s = fmaf(xv[c], swl[j * 8 + c], s);
      ov[j] = s;
    }
    *(float4*)(out0 + (long)n * 8) = make_float4(ov[0], ov[1], ov[2], ov[3]);
    *(float4*)(out0 + (long)n * 8 + 4) = make_float4(ov[4], ov[5], ov[6], ov[7]);
  }
}

extern "C" void kernel_launch(void* const* d_in, const int* in_sizes, int n_in,
                              void* d_out, int out_size, void* d_ws, size_t ws_size,
                              hipStream_t stream) {
  const float* feats   = (const float*)d_in[0];
  const int* nbr0      = (const int*)d_in[1];
  const int* nbr_d01   = (const int*)d_in[2];
  const int* nbr1      = (const int*)d_in[3];
  const int* nbr_d12   = (const int*)d_in[4];
  const int* nbr2      = (const int*)d_in[5];
  const int* nbr_d23   = (const int*)d_in[6];
  const int* nbr3      = (const int*)d_in[7];
  const int* nbr_u32   = (const int*)d_in[8];
  const int* nbr_u21   = (const int*)d_in[9];
  const int* nbr_u10   = (const int*)d_in[10];
  const float* w[10];
  const float* g[10];
  const float* b[10];
  for (int i = 0; i < 10; ++i) {
    w[i] = (const float*)d_in[11 + 3 * i];
    g[i] = (const float*)d_in[12 + 3 * i];
    b[i] = (const float*)d_in[13 + 3 * i];
  }
  const float* lin_w = (const float*)d_in[41];

  const int N0 = in_sizes[0] / 16;
  const int N1 = in_sizes[2] / 27;
  const int N2 = in_sizes[4] / 27;
  const int N3 = in_sizes[6] / 27;
  const float i0 = 1.f / N0, i1 = 1.f / N1, i2 = 1.f / N2, i3 = 1.f / N3;

  static const int CIv[10] = {16, 8, 16, 16, 32, 32, 64, 64, 32, 16};
  static const int COv[10] = {8, 16, 16, 32, 32, 64, 64, 32, 16, 8};

  // ---- workspace: fp32 stats region, then bf16 (ushort) region ----
  float* stats = (float*)d_ws;                       // 10 x NBUCKET x 128 floats
  unsigned short* u = (unsigned short*)(stats + 10 * NBUCKET * 128);

  unsigned short* yraw = u; u += (size_t)N1 * 32;    // bf16 y scratch

  unsigned short* wt[10];
  int wcum[11];
  wcum[0] = 0;
  for (int i = 0; i < 10; ++i) {
    wt[i] = u;
    int sz = 27 * CIv[i] * COv[i];
    u += sz;
    wcum[i + 1] = wcum[i] + sz;
  }
  unsigned short* featsb = u; u += (size_t)N0 * 16;
  unsigned short* c0f = u;    u += (size_t)N0 * 8;
  unsigned short* t1  = u;    u += (size_t)N1 * 16;
  unsigned short* c2f = u;    u += (size_t)N1 * 16;
  unsigned short* t2  = u;    u += (size_t)N2 * 32;
  unsigned short* c4f = u;    u += (size_t)N2 * 32;
  unsigned short* t3  = u;    u += (size_t)N3 * 64;
  unsigned short* t4  = u;    u += (size_t)N3 * 64;
  unsigned short* t5  = t2;   // reuse
  unsigned short* t6  = t1;   // reuse
  float* out0 = (float*)d_out;
  float* x0   = (float*)d_out + (size_t)N0 * 8;

  float* s[10];
  for (int i = 0; i < 10; ++i) s[i] = stats + i * NBUCKET * 128;

  // ---- prep (grid-stride) ----
  PrepArgs pa;
  for (int i = 0; i < 10; ++i) {
    pa.w[i] = w[i]; pa.wt[i] = wt[i];
    pa.ci[i] = CIv[i]; pa.co[i] = COv[i];
    pa.wcum[i] = wcum[i];
  }
  pa.wcum[10] = wcum[10];
  pa.feats = feats; pa.featsb = featsb;
  pa.nfeat4 = N0 * 16 / 4;
  pa.stats = stats;
  long prep_total = (10 * NBUCKET * 128 / 4) + pa.nfeat4 + wcum[10];
  prep_kernel<<<imin((int)((prep_total + 255) / 256), 2048), 256, 0, stream>>>(pa, prep_total);

  auto bgrid = [](long nout, int co) {
    return imin((int)((nout * co / 4 + 255) / 256), 1024);
  };

  int tb0 = cdiv(N0, 64), tb1 = cdiv(N1, 64), tb2 = cdiv(N2, 64), tb3 = cdiv(N3, 64);

  // conv0: 16->8 @ N0
  conv_mfma<16, 8, 6><<<dim3(tb0, 1), 256, 0, stream>>>(featsb, nbr0, wt[0], yraw, s[0], N0);
  bn_relu_bf16<8><<<bgrid(N0, 8), 256, 0, stream>>>(yraw, s[0], g[0], b[0], nullptr, c0f, N0, i0);

  // conv1: 8->16 down to N1
  conv_mfma<8, 16, 6><<<dim3(tb1, 1), 256, 0, stream>>>(c0f, nbr_d01, wt[1], yraw, s[1], N1);
  bn_relu_bf16<16><<<bgrid(N1, 16), 256, 0, stream>>>(yraw, s[1], g[1], b[1], nullptr, t1, N1, i1);

  // conv2: 16->16 @ N1
  conv_mfma<16, 16, 5><<<dim3(tb1, 1), 256, 0, stream>>>(t1, nbr1, wt[2], yraw, s[2], N1);
  bn_relu_bf16<16><<<bgrid(N1, 16), 256, 0, stream>>>(yraw, s[2], g[2], b[2], nullptr, c2f, N1, i1);

  // conv3: 16->32 down to N2
  conv_mfma<16, 32, 5><<<dim3(tb2, 2), 256, 0, stream>>>(c2f, nbr_d12, wt[3], yraw, s[3], N2);
  bn_relu_bf16<32><<<bgrid(N2, 32), 256, 0, stream>>>(yraw, s[3], g[3], b[3], nullptr, t2, N2, i2);

  // conv4: 32->32 @ N2
  conv_mfma<32, 32, 3><<<dim3(tb2, 2), 256, 0, stream>>>(t2, nbr2, wt[4], yraw, s[4], N2);
  bn_relu_bf16<32><<<bgrid(N2, 32), 256, 0, stream>>>(yraw, s[4], g[4], b[4], nullptr, c4f, N2, i2);

  // conv5: 32->64 down to N3
  conv_mfma<32, 64, 3><<<dim3(tb3, 4), 256, 0, stream>>>(c4f, nbr_d23, wt[5], yraw, s[5], N3);
  bn_relu_bf16<64><<<bgrid(N3, 64), 256, 0, stream>>>(yraw, s[5], g[5], b[5], nullptr, t3, N3, i3);

  // conv6: 64->64 @ N3
  conv_mfma<64, 64, 2><<<dim3(tb3, 4), 256, 0, stream>>>(t3, nbr3, wt[6], yraw, s[6], N3);
  bn_relu_bf16<64><<<bgrid(N3, 64), 256, 0, stream>>>(yraw, s[6], g[6], b[6], nullptr, t4, N3, i3);

  // conv7: 64->32 up to N2; x2 = c4f + relu(bn(y7))
  conv_mfma<64, 32, 2><<<dim3(tb2, 2), 256, 0, stream>>>(t4, nbr_u32, wt[7], yraw, s[7], N2);
  bn_relu_bf16<32><<<bgrid(N2, 32), 256, 0, stream>>>(yraw, s[7], g[7], b[7], c4f, t5, N2, i2);

  // conv8: 32->16 up to N1; x1 = c2f + relu(bn(y8))
  conv_mfma<32, 16, 3><<<dim3(tb1, 1), 256, 0, stream>>>(t5, nbr_u21, wt[8], yraw, s[8], N1);
  bn_relu_bf16<16><<<bgrid(N1, 16), 256, 0, stream>>>(yraw, s[8], g[8], b[8], c2f, t6, N1, i1);

  // conv9: 16->8 up to N0; y9 bf16 in yraw
  conv_mfma<16, 8, 6><<<dim3(tb0, 1), 256, 0, stream>>>(t6, nbr_u10, wt[9], yraw, s[9], N0);

  // tail: x0 = c0f + relu(bn(y9)); out0 = x0 @ lin_w.T
  tail_kernel<<<imin(cdiv(N0, 256), 1024), 256, 0, stream>>>(
      c0f, s[9], g[9], b[9], i0, lin_w, yraw, out0, x0, N0);
}

// Round 6
// 426.681 us; speedup vs baseline: 4.2945x; 1.0036x over previous
//
#include <hip/hip_runtime.h>

#define EPSV 1e-5f
#define NBUCKET 64

typedef __attribute__((ext_vector_type(8))) short short8;
typedef __attribute__((ext_vector_type(4))) float float4v;

static inline int cdiv(int a, int b) { return (a + b - 1) / b; }
static inline int imin(int a, int b) { return a < b ? a : b; }

__device__ inline unsigned short f2bf(float x) {
  unsigned u = __float_as_uint(x);
  return (unsigned short)((u + 0x7FFFu + ((u >> 16) & 1u)) >> 16);
}
__device__ inline float bf2f(unsigned short u) {
  return __uint_as_float(((unsigned)u) << 16);
}

struct PrepArgs {
  const float* w[10];
  unsigned short* wt[10];
  int ci[10];
  int co[10];
  int wcum[11];
  const float* feats;
  unsigned short* featsb;
  int nfeat4;
  float* stats;
};

// grid-stride: zero stats + feats fp32->bf16 + weights fp32->bf16 transposed [27][CO][CI]
__global__ __launch_bounds__(256) void prep_kernel(PrepArgs p, long total) {
  const int nstat4 = 10 * NBUCKET * 128 / 4;
  for (long tid0 = (long)blockIdx.x * 256 + threadIdx.x; tid0 < total;
       tid0 += (long)gridDim.x * 256) {
    long tid = tid0;
    if (tid < nstat4) {
      ((float4*)p.stats)[tid] = make_float4(0.f, 0.f, 0.f, 0.f);
      continue;
    }
    tid -= nstat4;
    if (tid < p.nfeat4) {
      float4 v = ((const float4*)p.feats)[tid];
      ushort4 r;
      r.x = f2bf(v.x); r.y = f2bf(v.y); r.z = f2bf(v.z); r.w = f2bf(v.w);
      ((ushort4*)p.featsb)[tid] = r;
      continue;
    }
    tid -= p.nfeat4;
    if (tid >= p.wcum[10]) continue;
    int i = 0;
    while (tid >= p.wcum[i + 1]) ++i;
    int e = (int)(tid - p.wcum[i]);
    int ci = p.ci[i], co = p.co[i];
    int k = e / (ci * co);
    int r = e - k * (ci * co);
    int o = r / ci;
    int c = r - o * ci;
    p.wt[i][((long)k * co + o) * ci + c] = f2bf(p.w[i][((long)k * ci + c) * co + o]);
  }
}

// ================= MFMA gather-GEMM conv: deep-MLP variant =================
// CI<=16: TWO 64-row tiles per block; all 2*NCHUNK gathers issued before any MFMA
// (sched_barrier(0) pins the phase split) -> ~28 loads in flight per wave.
// CI==32: one tile, fully-resident A[27] -> 27 loads in flight.
// CI==64: one tile, 9-group double-buffer (register budget).
// MINW=2 (cap 256 VGPR) so the compiler is never forced to serialize the gather batch.
template<int CI, int CO, int MINW>
__global__ __launch_bounds__(256, MINW) void conv_mfma(
    const unsigned short* __restrict__ f, const int* __restrict__ nbr,
    const unsigned short* __restrict__ wt, unsigned short* __restrict__ y,
    float* __restrict__ stats, int nout) {
  constexpr int NCHUNK = (CI == 8) ? 7 : (CI == 16) ? 14 : (CI == 32) ? 27 : 54;
  constexpr int CIP = (CI == 64) ? 64 : (CI == 32) ? 40 : (CI == 16) ? 24 : 12;
  constexpr int RB = (CO < 16) ? CO : 16;  // B rows stored (CO=8 -> 8)
  constexpr bool TWO = (CI <= 16);
  constexpr int NT = TWO ? 2 : 1;

  __shared__ int nbrT[NT * 64 * 27];
  __shared__ unsigned short Bs[27 * RB * CIP];

  const int tid = threadIdx.x;
  const int lane = tid & 63;
  const int wid = tid >> 6;
  const int m = lane & 15;
  const int mm = m & (RB - 1);  // clamped B row for dead lanes (RB power of 2)
  const int quad = lane >> 4;
  const int cbase = blockIdx.y * 16;
  const int co = cbase + m;
  const bool cok = co < CO;

  auto tapof = [&](int c) -> int {
    if constexpr (CI == 8) return c * 4 + quad;
    else if constexpr (CI == 16) return c * 2 + (quad >> 1);
    else if constexpr (CI == 32) return c;
    else return c >> 1;
  };
  auto cioof = [&](int c) -> int {
    if constexpr (CI == 8) return 0;
    else if constexpr (CI == 16) return (quad & 1) * 8;
    else if constexpr (CI == 32) return quad * 8;
    else return ((c & 1) << 5) + quad * 8;
  };
  // LDS B address (short index) for [tap][row][cio]
  auto baddr = [&](int tap, int r, int cio) -> int {
    if constexpr (CI == 64) {
      int byt = (tap * 16 + r) * 128 + cio * 2;
      byt ^= (r & 7) << 4;  // XOR-swizzle 16B slot within the 128B row
      return byt >> 1;
    } else {
      return (tap * RB + r) * CIP + cio;
    }
  };

  const int rowb0 = blockIdx.x * (NT * 64);

  // ---- cooperative weight-slice load into LDS ----
  {
    constexpr int NC8 = CI / 8;
    for (int t = tid; t < 27 * RB * NC8; t += 256) {
      int tap = t / (RB * NC8);
      int r = t - tap * (RB * NC8);
      int mo = r / NC8;
      int c8 = (r - mo * NC8) * 8;
      short8 v;
#pragma unroll
      for (int q = 0; q < 8; ++q) v[q] = 0;
      int c = cbase + mo;
      if (c < CO) v = *(const short8*)(wt + ((long)tap * CO + c) * CI + c8);
      *(short8*)&Bs[baddr(tap, mo, c8)] = v;
    }
  }
  // ---- cooperative nbr stage: contiguous int4 loads (NT tiles) ----
  {
    const long base = (long)rowb0 * 27;
    const long lim = (long)nout * 27;
    for (int j = tid; j < NT * 432; j += 256) {
      long g = base + j * 4;
      int4 v;
      if (g + 4 <= lim) {
        v = *(const int4*)(nbr + g);
      } else {
        v.x = (g + 0 < lim) ? nbr[g + 0] : -1;
        v.y = (g + 1 < lim) ? nbr[g + 1] : -1;
        v.z = (g + 2 < lim) ? nbr[g + 2] : -1;
        v.w = (g + 3 < lim) ? nbr[g + 3] : -1;
      }
      *(int4*)&nbrT[j * 4] = v;
    }
  }
  __syncthreads();

  const int rowb = rowb0 + wid * 16;
  const int lrow = (wid * 16 + m) * 27;
  float sum = 0.f, sq = 0.f;

  if constexpr (TWO) {
    int idx0[NCHUNK], idx1[NCHUNK];
#pragma unroll
    for (int c = 0; c < NCHUNK; ++c) {
      int tap = tapof(c);
      idx0[c] = (tap < 27) ? nbrT[lrow + tap] : -1;
      idx1[c] = (tap < 27) ? nbrT[1728 + lrow + tap] : -1;
    }
    short8 A0[NCHUNK], A1[NCHUNK];
#pragma unroll
    for (int c = 0; c < NCHUNK; ++c) {
      short8 a;
#pragma unroll
      for (int q = 0; q < 8; ++q) a[q] = 0;
      if (idx0[c] >= 0) a = *(const short8*)(f + (long)idx0[c] * CI + cioof(c));
      A0[c] = a;
    }
#pragma unroll
    for (int c = 0; c < NCHUNK; ++c) {
      short8 a;
#pragma unroll
      for (int q = 0; q < 8; ++q) a[q] = 0;
      if (idx1[c] >= 0) a = *(const short8*)(f + (long)idx1[c] * CI + cioof(c));
      A1[c] = a;
    }
    __builtin_amdgcn_sched_barrier(0);  // all gathers issued before MFMA phase
    float4v acc0 = {0.f, 0.f, 0.f, 0.f};
    float4v acc1 = {0.f, 0.f, 0.f, 0.f};
#pragma unroll
    for (int c = 0; c < NCHUNK; ++c) {
      int tap = tapof(c);
      int tapc = tap < 27 ? tap : 26;  // A=0 masks the clamped B
      short8 bf = *(const short8*)&Bs[baddr(tapc, mm, cioof(c))];
      acc0 = __builtin_amdgcn_mfma_f32_16x16x32_bf16(A0[c], bf, acc0, 0, 0, 0);
      acc1 = __builtin_amdgcn_mfma_f32_16x16x32_bf16(A1[c], bf, acc1, 0, 0, 0);
    }
#pragma unroll
    for (int r = 0; r < 4; ++r) {
      float v0 = acc0[r];
      int o0 = rowb + quad * 4 + r;
      if (cok && o0 < nout) y[(long)o0 * CO + co] = f2bf(v0);
      sum += v0;
      sq = fmaf(v0, v0, sq);
      float v1 = acc1[r];
      int o1 = rowb + 64 + quad * 4 + r;
      if (cok && o1 < nout) y[(long)o1 * CO + co] = f2bf(v1);
      sum += v1;
      sq = fmaf(v1, v1, sq);
    }
  } else if constexpr (CI == 32) {
    int idxs[27];
#pragma unroll
    for (int t = 0; t < 27; ++t) idxs[t] = nbrT[lrow + t];
    short8 A[27];
#pragma unroll
    for (int c = 0; c < 27; ++c) {
      short8 a;
#pragma unroll
      for (int q = 0; q < 8; ++q) a[q] = 0;
      if (idxs[c] >= 0) a = *(const short8*)(f + (long)idxs[c] * 32 + quad * 8);
      A[c] = a;
    }
    __builtin_amdgcn_sched_barrier(0);
    float4v acc = {0.f, 0.f, 0.f, 0.f};
#pragma unroll
    for (int c = 0; c < 27; ++c) {
      short8 bf = *(const short8*)&Bs[baddr(c, mm, quad * 8)];
      acc = __builtin_amdgcn_mfma_f32_16x16x32_bf16(A[c], bf, acc, 0, 0, 0);
    }
#pragma unroll
    for (int r = 0; r < 4; ++r) {
      float v = acc[r];
      int orow = rowb + quad * 4 + r;
      if (cok && orow < nout) y[(long)orow * CO + co] = f2bf(v);
      sum += v;
      sq = fmaf(v, v, sq);
    }
  } else {  // CI == 64
    constexpr int G = 9;
    constexpr int NG = NCHUNK / G;
    short8 A[2][G];
    auto load_group = [&](int g, int bi) {
#pragma unroll
      for (int j = 0; j < G; ++j) {
        const int c = g * G + j;
        const int tap = tapof(c);
        int idx = nbrT[lrow + tap];
        short8 a;
#pragma unroll
        for (int q = 0; q < 8; ++q) a[q] = 0;
        if (idx >= 0) a = *(const short8*)(f + (long)idx * CI + cioof(c));
        A[bi][j] = a;
      }
    };
    float4v acc = {0.f, 0.f, 0.f, 0.f};
    load_group(0, 0);
#pragma unroll
    for (int g = 0; g < NG; ++g) {
      const int cur = g & 1;
      if (g + 1 < NG) load_group(g + 1, cur ^ 1);
#pragma unroll
      for (int j = 0; j < G; ++j) {
        const int c = g * G + j;
        short8 bf = *(const short8*)&Bs[baddr(tapof(c), mm, cioof(c))];
        acc = __builtin_amdgcn_mfma_f32_16x16x32_bf16(A[cur][j], bf, acc, 0, 0, 0);
      }
    }
#pragma unroll
    for (int r = 0; r < 4; ++r) {
      float v = acc[r];
      int orow = rowb + quad * 4 + r;
      if (cok && orow < nout) y[(long)orow * CO + co] = f2bf(v);
      sum += v;
      sq = fmaf(v, v, sq);
    }
  }

  // one atomic pair per wave
  sum += __shfl_xor(sum, 16); sq += __shfl_xor(sq, 16);
  sum += __shfl_xor(sum, 32); sq += __shfl_xor(sq, 32);
  if (quad == 0 && cok) {
    float* st = stats + ((((unsigned)blockIdx.x * 4 + wid) & (NBUCKET - 1)) << 7);
    atomicAdd(&st[co], sum);
    atomicAdd(&st[64 + co], sq);
  }
}

// ---- BN+ReLU (+bf16 skip), bf16 y -> bf16 feature map, grid-stride ----
template<int CO>
__global__ __launch_bounds__(256) void bn_relu_bf16(
    const unsigned short* __restrict__ y, const float* __restrict__ stats,
    const float* __restrict__ g, const float* __restrict__ b,
    const unsigned short* __restrict__ skip, unsigned short* __restrict__ out,
    int nout, float inv_n) {
  __shared__ float sA[CO], sC[CO];
  if ((int)threadIdx.x < CO) {
    int o = threadIdx.x;
    float su = 0.f, sq = 0.f;
#pragma unroll 8
    for (int bk = 0; bk < NBUCKET; ++bk) {
      su += stats[bk * 128 + o];
      sq += stats[bk * 128 + 64 + o];
    }
    float mu = su * inv_n;
    float var = sq * inv_n - mu * mu;
    float a = g[o] * rsqrtf(var + EPSV);
    sA[o] = a;
    sC[o] = fmaf(-mu, a, b[o]);
  }
  __syncthreads();
  long total4 = (long)nout * CO / 4;
  for (long i4 = (long)blockIdx.x * 256 + threadIdx.x; i4 < total4;
       i4 += (long)gridDim.x * 256) {
    int o = (int)((i4 * 4) % CO);
    ushort4 v = ((const ushort4*)y)[i4];
    float vv[4] = {bf2f(v.x), bf2f(v.y), bf2f(v.z), bf2f(v.w)};
    unsigned short rr[4];
#pragma unroll
    for (int j = 0; j < 4; ++j) {
      float x = fmaxf(fmaf(vv[j], sA[o + j], sC[o + j]), 0.f);
      if (skip) x += bf2f(skip[i4 * 4 + j]);
      rr[j] = f2bf(x);
    }
    ushort4 r;
    r.x = rr[0]; r.y = rr[1]; r.z = rr[2]; r.w = rr[3];
    ((ushort4*)out)[i4] = r;
  }
}

// ---- fused tail: x0 = c0f + relu(bn(y9)); out0 = x0 @ lin_w.T, grid-stride ----
__global__ __launch_bounds__(256) void tail_kernel(
    const unsigned short* __restrict__ c0f, const float* __restrict__ st9,
    const float* __restrict__ g9, const float* __restrict__ b9, float inv_n,
    const float* __restrict__ lin_w, const unsigned short* __restrict__ y9,
    float* __restrict__ out0, float* __restrict__ x0, int n0) {
  __shared__ float swl[64];
  __shared__ float sbn[16];
  if (threadIdx.x < 64) swl[threadIdx.x] = lin_w[threadIdx.x];
  if (threadIdx.x < 8) {
    int o = threadIdx.x;
    float su = 0.f, sq = 0.f;
#pragma unroll 8
    for (int bk = 0; bk < NBUCKET; ++bk) {
      su += st9[bk * 128 + o];
      sq += st9[bk * 128 + 64 + o];
    }
    float mu = su * inv_n;
    float var = sq * inv_n - mu * mu;
    float a = g9[o] * rsqrtf(var + EPSV);
    sbn[o] = a;
    sbn[8 + o] = fmaf(-mu, a, b9[o]);
  }
  __syncthreads();
  for (int n = blockIdx.x * 256 + (int)threadIdx.x; n < n0; n += gridDim.x * 256) {
    const ushort4* pr = (const ushort4*)(y9 + (long)n * 8);
    ushort4 r0 = pr[0], r1 = pr[1];
    unsigned short rw[8] = {r0.x, r0.y, r0.z, r0.w, r1.x, r1.y, r1.z, r1.w};
    const ushort4* pc = (const ushort4*)(c0f + (long)n * 8);
    ushort4 c0 = pc[0], c1 = pc[1];
    unsigned short cs[8] = {c0.x, c0.y, c0.z, c0.w, c1.x, c1.y, c1.z, c1.w};
    float xv[8];
#pragma unroll
    for (int c = 0; c < 8; ++c)
      xv[c] = bf2f(cs[c]) + fmaxf(fmaf(bf2f(rw[c]), sbn[c], sbn[8 + c]), 0.f);
    *(float4*)(x0 + (long)n * 8) = make_float4(xv[0], xv[1], xv[2], xv[3]);
    *(float4*)(x0 + (long)n * 8 + 4) = make_float4(xv[4], xv[5], xv[6], xv[7]);
    float ov[8];
#pragma unroll
    for (int j = 0; j < 8; ++j) {
      float s = 0.f;
#pragma unroll
      for (int c = 0; c < 8; ++c) s = fmaf(xv[c], swl[j * 8 + c], s);
      ov[j] = s;
    }
    *(float4*)(out0 + (long)n * 8) = make_float4(ov[0], ov[1], ov[2], ov[3]);
    *(float4*)(out0 + (long)n * 8 + 4) = make_float4(ov[4], ov[5], ov[6], ov[7]);
  }
}

extern "C" void kernel_launch(void* const* d_in, const int* in_sizes, int n_in,
                              void* d_out, int out_size, void* d_ws, size_t ws_size,
                              hipStream_t stream) {
  const float* feats   = (const float*)d_in[0];
  const int* nbr0      = (const int*)d_in[1];
  const int* nbr_d01   = (const int*)d_in[2];
  const int* nbr1      = (const int*)d_in[3];
  const int* nbr_d12   = (const int*)d_in[4];
  const int* nbr2      = (const int*)d_in[5];
  const int* nbr_d23   = (const int*)d_in[6];
  const int* nbr3      = (const int*)d_in[7];
  const int* nbr_u32   = (const int*)d_in[8];
  const int* nbr_u21   = (const int*)d_in[9];
  const int* nbr_u10   = (const int*)d_in[10];
  const float* w[10];
  const float* g[10];
  const float* b[10];
  for (int i = 0; i < 10; ++i) {
    w[i] = (const float*)d_in[11 + 3 * i];
    g[i] = (const float*)d_in[12 + 3 * i];
    b[i] = (const float*)d_in[13 + 3 * i];
  }
  const float* lin_w = (const float*)d_in[41];

  const int N0 = in_sizes[0] / 16;
  const int N1 = in_sizes[2] / 27;
  const int N2 = in_sizes[4] / 27;
  const int N3 = in_sizes[6] / 27;
  const float i0 = 1.f / N0, i1 = 1.f / N1, i2 = 1.f / N2, i3 = 1.f / N3;

  static const int CIv[10] = {16, 8, 16, 16, 32, 32, 64, 64, 32, 16};
  static const int COv[10] = {8, 16, 16, 32, 32, 64, 64, 32, 16, 8};

  // ---- workspace: fp32 stats region, then bf16 (ushort) region ----
  float* stats = (float*)d_ws;                       // 10 x NBUCKET x 128 floats
  unsigned short* u = (unsigned short*)(stats + 10 * NBUCKET * 128);

  unsigned short* yraw = u; u += (size_t)N1 * 32;    // bf16 y scratch

  unsigned short* wt[10];
  int wcum[11];
  wcum[0] = 0;
  for (int i = 0; i < 10; ++i) {
    wt[i] = u;
    int sz = 27 * CIv[i] * COv[i];
    u += sz;
    wcum[i + 1] = wcum[i] + sz;
  }
  unsigned short* featsb = u; u += (size_t)N0 * 16;
  unsigned short* c0f = u;    u += (size_t)N0 * 8;
  unsigned short* t1  = u;    u += (size_t)N1 * 16;
  unsigned short* c2f = u;    u += (size_t)N1 * 16;
  unsigned short* t2  = u;    u += (size_t)N2 * 32;
  unsigned short* c4f = u;    u += (size_t)N2 * 32;
  unsigned short* t3  = u;    u += (size_t)N3 * 64;
  unsigned short* t4  = u;    u += (size_t)N3 * 64;
  unsigned short* t5  = t2;   // reuse
  unsigned short* t6  = t1;   // reuse
  float* out0 = (float*)d_out;
  float* x0   = (float*)d_out + (size_t)N0 * 8;

  float* s[10];
  for (int i = 0; i < 10; ++i) s[i] = stats + i * NBUCKET * 128;

  // ---- prep (grid-stride) ----
  PrepArgs pa;
  for (int i = 0; i < 10; ++i) {
    pa.w[i] = w[i]; pa.wt[i] = wt[i];
    pa.ci[i] = CIv[i]; pa.co[i] = COv[i];
    pa.wcum[i] = wcum[i];
  }
  pa.wcum[10] = wcum[10];
  pa.feats = feats; pa.featsb = featsb;
  pa.nfeat4 = N0 * 16 / 4;
  pa.stats = stats;
  long prep_total = (10 * NBUCKET * 128 / 4) + pa.nfeat4 + wcum[10];
  prep_kernel<<<imin((int)((prep_total + 255) / 256), 2048), 256, 0, stream>>>(pa, prep_total);

  auto bgrid = [](long nout, int co) {
    return imin((int)((nout * co / 4 + 255) / 256), 1024);
  };

  // grids: 128 rows/block for CI<=16 (two tiles), 64 rows/block otherwise
  int g2_0 = cdiv(N0, 128), g2_1 = cdiv(N1, 128), g2_2 = cdiv(N2, 128);
  int g1_1 = cdiv(N1, 64), g1_2 = cdiv(N2, 64), g1_3 = cdiv(N3, 64);

  // conv0: 16->8 @ N0
  conv_mfma<16, 8, 2><<<dim3(g2_0, 1), 256, 0, stream>>>(featsb, nbr0, wt[0], yraw, s[0], N0);
  bn_relu_bf16<8><<<bgrid(N0, 8), 256, 0, stream>>>(yraw, s[0], g[0], b[0], nullptr, c0f, N0, i0);

  // conv1: 8->16 down to N1
  conv_mfma<8, 16, 4><<<dim3(g2_1, 1), 256, 0, stream>>>(c0f, nbr_d01, wt[1], yraw, s[1], N1);
  bn_relu_bf16<16><<<bgrid(N1, 16), 256, 0, stream>>>(yraw, s[1], g[1], b[1], nullptr, t1, N1, i1);

  // conv2: 16->16 @ N1
  conv_mfma<16, 16, 2><<<dim3(g2_1, 1), 256, 0, stream>>>(t1, nbr1, wt[2], yraw, s[2], N1);
  bn_relu_bf16<16><<<bgrid(N1, 16), 256, 0, stream>>>(yraw, s[2], g[2], b[2], nullptr, c2f, N1, i1);

  // conv3: 16->32 down to N2
  conv_mfma<16, 32, 2><<<dim3(g2_2, 2), 256, 0, stream>>>(c2f, nbr_d12, wt[3], yraw, s[3], N2);
  bn_relu_bf16<32><<<bgrid(N2, 32), 256, 0, stream>>>(yraw, s[3], g[3], b[3], nullptr, t2, N2, i2);

  // conv4: 32->32 @ N2
  conv_mfma<32, 32, 2><<<dim3(g1_2, 2), 256, 0, stream>>>(t2, nbr2, wt[4], yraw, s[4], N2);
  bn_relu_bf16<32><<<bgrid(N2, 32), 256, 0, stream>>>(yraw, s[4], g[4], b[4], nullptr, c4f, N2, i2);

  // conv5: 32->64 down to N3
  conv_mfma<32, 64, 2><<<dim3(g1_3, 4), 256, 0, stream>>>(c4f, nbr_d23, wt[5], yraw, s[5], N3);
  bn_relu_bf16<64><<<bgrid(N3, 64), 256, 0, stream>>>(yraw, s[5], g[5], b[5], nullptr, t3, N3, i3);

  // conv6: 64->64 @ N3
  conv_mfma<64, 64, 2><<<dim3(g1_3, 4), 256, 0, stream>>>(t3, nbr3, wt[6], yraw, s[6], N3);
  bn_relu_bf16<64><<<bgrid(N3, 64), 256, 0, stream>>>(yraw, s[6], g[6], b[6], nullptr, t4, N3, i3);

  // conv7: 64->32 up to N2; x2 = c4f + relu(bn(y7))
  conv_mfma<64, 32, 2><<<dim3(g1_2, 2), 256, 0, stream>>>(t4, nbr_u32, wt[7], yraw, s[7], N2);
  bn_relu_bf16<32><<<bgrid(N2, 32), 256, 0, stream>>>(yraw, s[7], g[7], b[7], c4f, t5, N2, i2);

  // conv8: 32->16 up to N1; x1 = c2f + relu(bn(y8))
  conv_mfma<32, 16, 2><<<dim3(g1_1, 1), 256, 0, stream>>>(t5, nbr_u21, wt[8], yraw, s[8], N1);
  bn_relu_bf16<16><<<bgrid(N1, 16), 256, 0, stream>>>(yraw, s[8], g[8], b[8], c2f, t6, N1, i1);

  // conv9: 16->8 up to N0; y9 bf16 in yraw
  conv_mfma<16, 8, 2><<<dim3(g2_0, 1), 256, 0, stream>>>(t6, nbr_u10, wt[9], yraw, s[9], N0);

  // tail: x0 = c0f + relu(bn(y9)); out0 = x0 @ lin_w.T
  tail_kernel<<<imin(cdiv(N0, 256), 1024), 256, 0, stream>>>(
      c0f, s[9], g[9], b[9], i0, lin_w, yraw, out0, x0, N0);
}